// Round 1
// baseline (1848.048 us; speedup 1.0000x reference)
//
#include <hip/hip_runtime.h>
#include <hip/hip_bf16.h>
#include <math.h>

// N=50000, E=500000, SED=128, HID=64, H=2, F_node=128
// Layer1: in 256 (128 x + 128 const sent), out [N,2,64] -> concat 128
// Layer2: in 128, out [N,2,128] -> mean -> 128
// Edge head: [E,256] @ fc2t[256,128] -> relu -> dot fc3[128] -> sigmoid

__device__ __forceinline__ float wave_reduce_sum(float v) {
    #pragma unroll
    for (int off = 32; off > 0; off >>= 1) v += __shfl_down(v, off, 64);
    return v;
}

// ---- tiny precompute: sent vec, c1 (sent contribution through W1), fc2 transpose ----
__global__ void prep_kernel(const float* __restrict__ cls, const float* __restrict__ fc0_w,
                            const float* __restrict__ fc0_b, const float* __restrict__ W1,
                            const float* __restrict__ fc2_w,
                            float* __restrict__ c1, float* __restrict__ fc2t) {
    __shared__ float s_sent[128];
    int tid = threadIdx.x;
    if (tid < 128) {
        float acc = fc0_b[tid];
        const float* row = fc0_w + (size_t)tid * 768;
        for (int k = 0; k < 768; ++k) acc += row[k] * cls[k];
        s_sent[tid] = acc;
    }
    __syncthreads();
    if (tid < 128) {
        float acc = 0.f;
        for (int k = 0; k < 128; ++k) acc += s_sent[k] * W1[(128 + k) * 128 + tid];
        c1[tid] = acc;
    }
    // fc2_w [128,256] -> fc2t [256,128]
    for (int i = tid; i < 256 * 128; i += blockDim.x) {
        int j = i & 127;  // out channel
        int k = i >> 7;   // in channel
        fc2t[k * 128 + j] = fc2_w[j * 256 + k];
    }
}

// ---- GEMM1: h1pre = x @ W1[0:128,:] + c1 ; epilogue a_src1/a_dst1 [N,2] ----
__global__ void __launch_bounds__(128) gemm1_kernel(
        const float* __restrict__ x, const float* __restrict__ W1,
        const float* __restrict__ c1,
        const float* __restrict__ att_s, const float* __restrict__ att_d,
        float* __restrict__ h1pre, float* __restrict__ a_src, float* __restrict__ a_dst, int N) {
    __shared__ float xs[8][128];
    int tid = threadIdx.x;
    int base = blockIdx.x * 8;
    #pragma unroll
    for (int nd = 0; nd < 8; ++nd) {
        int n = base + nd;
        if (n < N) xs[nd][tid] = x[(size_t)n * 128 + tid];
    }
    __syncthreads();
    float cj = c1[tid];
    float acc[8];
    #pragma unroll
    for (int nd = 0; nd < 8; ++nd) acc[nd] = cj;
    for (int k = 0; k < 128; ++k) {
        float w = W1[k * 128 + tid];
        #pragma unroll
        for (int nd = 0; nd < 8; ++nd) acc[nd] += xs[nd][k] * w;
    }
    float asj = att_s[tid], adj = att_d[tid];
    int lane = tid & 63, h = tid >> 6;
    #pragma unroll
    for (int nd = 0; nd < 8; ++nd) {
        int n = base + nd;
        if (n >= N) break;
        h1pre[(size_t)n * 128 + tid] = acc[nd];
        float ps = wave_reduce_sum(acc[nd] * asj);
        float pd = wave_reduce_sum(acc[nd] * adj);
        if (lane == 0) { a_src[n * 2 + h] = ps; a_dst[n * 2 + h] = pd; }
    }
}

// ---- edge softmax denominator (shared by both layers) ----
__global__ void edge_softmax_kernel(const int* __restrict__ src, const int* __restrict__ dst,
                                    const float* __restrict__ a_src, const float* __restrict__ a_dst,
                                    float* __restrict__ ssum, int E) {
    int e = blockIdx.x * blockDim.x + threadIdx.x;
    if (e >= E) return;
    int s = src[e], d = dst[e];
    #pragma unroll
    for (int h = 0; h < 2; ++h) {
        float v = a_src[s * 2 + h] + a_dst[d * 2 + h];
        v = v > 0.f ? v : 0.2f * v;
        atomicAdd(&ssum[d * 2 + h], expf(v));
    }
}

// ---- layer1 aggregation: agg[dst, h*64+c] += h1pre[src, h*64+c] * alpha ----
__global__ void __launch_bounds__(256) edge_agg1_kernel(
        const int* __restrict__ src, const int* __restrict__ dst,
        const float* __restrict__ a_src, const float* __restrict__ a_dst,
        const float* __restrict__ ssum, const float* __restrict__ h1pre,
        float* __restrict__ agg, int E) {
    int e = blockIdx.x * 4 + (threadIdx.x >> 6);
    if (e >= E) return;
    int lane = threadIdx.x & 63;
    int s = src[e], d = dst[e];
    #pragma unroll
    for (int h = 0; h < 2; ++h) {
        float v = a_src[s * 2 + h] + a_dst[d * 2 + h];
        v = v > 0.f ? v : 0.2f * v;
        float alpha = expf(v) / (ssum[d * 2 + h] + 1e-16f);
        int j = h * 64 + lane;
        atomicAdd(&agg[(size_t)d * 128 + j], h1pre[(size_t)s * 128 + j] * alpha);
    }
}

// ---- elu(x + bias) in place ----
__global__ void elu_bias_kernel(float* __restrict__ a, const float* __restrict__ bias, int total) {
    int i = blockIdx.x * blockDim.x + threadIdx.x;
    if (i >= total) return;
    float v = a[i] + bias[i & 127];
    a[i] = v > 0.f ? v : expm1f(v);
}

// ---- GEMM2: h2pre = hmid @ W2 [128,256]; epilogue a_src2/a_dst2 ----
__global__ void __launch_bounds__(256) gemm2_kernel(
        const float* __restrict__ hmid, const float* __restrict__ W2,
        const float* __restrict__ att_s, const float* __restrict__ att_d,
        float* __restrict__ h2pre, float* __restrict__ a_src, float* __restrict__ a_dst, int N) {
    __shared__ float hs[8][128];
    __shared__ float red[4][8][2];
    int tid = threadIdx.x;
    int base = blockIdx.x * 8;
    for (int i = tid; i < 8 * 128; i += 256) {
        int nd = i >> 7, k = i & 127;
        int n = base + nd;
        if (n < N) hs[nd][k] = hmid[(size_t)n * 128 + k];
    }
    __syncthreads();
    float acc[8];
    #pragma unroll
    for (int nd = 0; nd < 8; ++nd) acc[nd] = 0.f;
    for (int k = 0; k < 128; ++k) {
        float w = W2[k * 256 + tid];
        #pragma unroll
        for (int nd = 0; nd < 8; ++nd) acc[nd] += hs[nd][k] * w;
    }
    float asj = att_s[tid], adj = att_d[tid];
    int lane = tid & 63, wv = tid >> 6;
    #pragma unroll
    for (int nd = 0; nd < 8; ++nd) {
        int n = base + nd;
        if (n < N) h2pre[(size_t)n * 256 + tid] = acc[nd];
        float ps = wave_reduce_sum(acc[nd] * asj);
        float pd = wave_reduce_sum(acc[nd] * adj);
        if (lane == 0) { red[wv][nd][0] = ps; red[wv][nd][1] = pd; }
    }
    __syncthreads();
    if (tid < 16) {
        int nd = tid >> 1, h = tid & 1;
        int n = base + nd;
        if (n < N) {
            a_src[n * 2 + h] = red[h * 2][nd][0] + red[h * 2 + 1][nd][0];
            a_dst[n * 2 + h] = red[h * 2][nd][1] + red[h * 2 + 1][nd][1];
        }
    }
}

// ---- layer2 aggregation with folded head-mean: h2acc[dst,c] += 0.5*alpha_h*h2pre[src,h*128+c] ----
__global__ void __launch_bounds__(256) edge_agg2_kernel(
        const int* __restrict__ src, const int* __restrict__ dst,
        const float* __restrict__ a_src, const float* __restrict__ a_dst,
        const float* __restrict__ ssum, const float* __restrict__ h2pre,
        float* __restrict__ agg, int E) {
    int e = blockIdx.x * 4 + (threadIdx.x >> 6);
    if (e >= E) return;
    int lane = threadIdx.x & 63;
    int s = src[e], d = dst[e];
    float al[2];
    #pragma unroll
    for (int h = 0; h < 2; ++h) {
        float v = a_src[s * 2 + h] + a_dst[d * 2 + h];
        v = v > 0.f ? v : 0.2f * v;
        al[h] = 0.5f * expf(v) / (ssum[d * 2 + h] + 1e-16f);
    }
    #pragma unroll
    for (int it = 0; it < 4; ++it) {
        int j = it * 64 + lane;
        int h = j >> 7;
        atomicAdd(&agg[(size_t)d * 128 + (j & 127)], h2pre[(size_t)s * 256 + j] * al[h]);
    }
}

__global__ void bias2_kernel(float* __restrict__ a, const float* __restrict__ bias, int total) {
    int i = blockIdx.x * blockDim.x + threadIdx.x;
    if (i >= total) return;
    a[i] += bias[i & 127];
}

// ---- edge head: 16 edges/block, 128 threads; z=relu(fc2t^T . cat + b); logit = z.fc3 ----
__global__ void __launch_bounds__(128) edge_head_kernel(
        const int* __restrict__ src, const int* __restrict__ dst,
        const float* __restrict__ h2, const float* __restrict__ fc2t,
        const float* __restrict__ fc2_b, const float* __restrict__ fc3_w,
        const float* __restrict__ fc3_b, float* __restrict__ out, int E) {
    __shared__ float cat[16][256];
    __shared__ float red[2][16];
    int tid = threadIdx.x;
    int base = blockIdx.x * 16;
    #pragma unroll
    for (int ed = 0; ed < 16; ++ed) {
        int e = base + ed;
        if (e < E) {
            int s = src[e], d = dst[e];
            cat[ed][tid] = h2[(size_t)s * 128 + tid];
            cat[ed][128 + tid] = h2[(size_t)d * 128 + tid];
        }
    }
    __syncthreads();
    float bj = fc2_b[tid];
    float acc[16];
    #pragma unroll
    for (int ed = 0; ed < 16; ++ed) acc[ed] = bj;
    for (int k = 0; k < 256; k += 4) {
        float w0 = fc2t[(k + 0) * 128 + tid];
        float w1 = fc2t[(k + 1) * 128 + tid];
        float w2 = fc2t[(k + 2) * 128 + tid];
        float w3 = fc2t[(k + 3) * 128 + tid];
        #pragma unroll
        for (int ed = 0; ed < 16; ++ed) {
            float4 c4 = *(const float4*)&cat[ed][k];
            acc[ed] += c4.x * w0 + c4.y * w1 + c4.z * w2 + c4.w * w3;
        }
    }
    float f3 = fc3_w[tid];
    int lane = tid & 63, wv = tid >> 6;
    #pragma unroll
    for (int ed = 0; ed < 16; ++ed) {
        float p = wave_reduce_sum(fmaxf(acc[ed], 0.f) * f3);
        if (lane == 0) red[wv][ed] = p;
    }
    __syncthreads();
    if (tid < 16 && base + tid < E) {
        float logit = red[0][tid] + red[1][tid] + fc3_b[0];
        out[base + tid] = 1.f / (1.f + expf(-logit));
    }
}

extern "C" void kernel_launch(void* const* d_in, const int* in_sizes, int n_in,
                              void* d_out, int out_size, void* d_ws, size_t ws_size,
                              hipStream_t stream) {
    const float* x      = (const float*)d_in[0];
    const int*   ei     = (const int*)d_in[1];
    const float* cls    = (const float*)d_in[2];
    const float* fc0_w  = (const float*)d_in[3];
    const float* fc0_b  = (const float*)d_in[4];
    const float* W1     = (const float*)d_in[5];
    const float* att_s1 = (const float*)d_in[6];
    const float* att_d1 = (const float*)d_in[7];
    const float* bias1  = (const float*)d_in[8];
    const float* W2     = (const float*)d_in[9];
    const float* att_s2 = (const float*)d_in[10];
    const float* att_d2 = (const float*)d_in[11];
    const float* bias2  = (const float*)d_in[12];
    const float* fc2_w  = (const float*)d_in[13];
    const float* fc2_b  = (const float*)d_in[14];
    const float* fc3_w  = (const float*)d_in[15];
    const float* fc3_b  = (const float*)d_in[16];
    float* out = (float*)d_out;

    int N = in_sizes[0] / 128;
    int E = in_sizes[1] / 2;
    const int* src = ei;
    const int* dst = ei + E;

    float* w = (float*)d_ws;
    size_t off = 0;
    auto alloc = [&](size_t n) { float* p = w + off; off += (n + 63) & ~(size_t)63; return p; };
    float* c1    = alloc(128);
    float* fc2t  = alloc(256 * 128);
    float* a_s1  = alloc((size_t)N * 2);
    float* a_d1  = alloc((size_t)N * 2);
    float* a_s2  = alloc((size_t)N * 2);
    float* a_d2  = alloc((size_t)N * 2);
    float* s1    = alloc((size_t)N * 2);
    float* s2    = alloc((size_t)N * 2);
    float* h1pre = alloc((size_t)N * 128);  // later reused as h2 accumulator / h2
    float* agg1  = alloc((size_t)N * 128);  // becomes hmid (ELU in place)
    float* h2pre = alloc((size_t)N * 256);

    hipMemsetAsync(s1, 0, sizeof(float) * (size_t)N * 2, stream);
    hipMemsetAsync(s2, 0, sizeof(float) * (size_t)N * 2, stream);
    hipMemsetAsync(agg1, 0, sizeof(float) * (size_t)N * 128, stream);

    prep_kernel<<<1, 256, 0, stream>>>(cls, fc0_w, fc0_b, W1, fc2_w, c1, fc2t);
    gemm1_kernel<<<(N + 7) / 8, 128, 0, stream>>>(x, W1, c1, att_s1, att_d1, h1pre, a_s1, a_d1, N);
    edge_softmax_kernel<<<(E + 255) / 256, 256, 0, stream>>>(src, dst, a_s1, a_d1, s1, E);
    edge_agg1_kernel<<<(E + 3) / 4, 256, 0, stream>>>(src, dst, a_s1, a_d1, s1, h1pre, agg1, E);
    elu_bias_kernel<<<(N * 128 + 255) / 256, 256, 0, stream>>>(agg1, bias1, N * 128);
    // h1pre is dead now -> reuse as layer-2 accumulator
    hipMemsetAsync(h1pre, 0, sizeof(float) * (size_t)N * 128, stream);
    gemm2_kernel<<<(N + 7) / 8, 256, 0, stream>>>(agg1, W2, att_s2, att_d2, h2pre, a_s2, a_d2, N);
    edge_softmax_kernel<<<(E + 255) / 256, 256, 0, stream>>>(src, dst, a_s2, a_d2, s2, E);
    edge_agg2_kernel<<<(E + 3) / 4, 256, 0, stream>>>(src, dst, a_s2, a_d2, s2, h2pre, h1pre, E);
    bias2_kernel<<<(N * 128 + 255) / 256, 256, 0, stream>>>(h1pre, bias2, N * 128);
    edge_head_kernel<<<(E + 15) / 16, 128, 0, stream>>>(src, dst, h1pre, fc2t, fc2_b, fc3_w, fc3_b, out, E);
}

// Round 2
// 1163.854 us; speedup vs baseline: 1.5879x; 1.5879x over previous
//
#include <hip/hip_runtime.h>
#include <hip/hip_bf16.h>
#include <math.h>

// N=50000, E=500000, SED=128, HID=64, H=2, F_node=128
// Edge head is now an MFMA bf16 gather-GEMM: [E,256] @ [256,128], K=256.

typedef short short8 __attribute__((ext_vector_type(8)));
typedef float floatx4 __attribute__((ext_vector_type(4)));

__device__ __forceinline__ float wave_reduce_sum(float v) {
    #pragma unroll
    for (int off = 32; off > 0; off >>= 1) v += __shfl_down(v, off, 64);
    return v;
}

// ---- tiny precompute: sent vec, c1 (sent contribution through W1), fc2 B-fragment table ----
__global__ void prep_kernel(const float* __restrict__ cls, const float* __restrict__ fc0_w,
                            const float* __restrict__ fc0_b, const float* __restrict__ W1,
                            const float* __restrict__ fc2_w,
                            float* __restrict__ c1, __hip_bfloat16* __restrict__ bfrag) {
    __shared__ float s_sent[128];
    int tid = threadIdx.x;
    if (tid < 128) {
        float acc = fc0_b[tid];
        const float* row = fc0_w + (size_t)tid * 768;
        for (int k = 0; k < 768; ++k) acc += row[k] * cls[k];
        s_sent[tid] = acc;
    }
    __syncthreads();
    if (tid < 128) {
        float acc = 0.f;
        for (int k = 0; k < 128; ++k) acc += s_sent[k] * W1[(128 + k) * 128 + tid];
        c1[tid] = acc;
    }
    // B-fragment table for mfma_f32_16x16x32_bf16:
    // B[k][n] with k = kt*32 + (lane>>4)*8 + j, n = nt*16 + (lane&15)
    // stored at bfrag[((kt*8 + nt)*64 + lane)*8 + j]; B[k][n] = fc2_w[n*256 + k]
    for (int i = tid; i < 8 * 8 * 64 * 8; i += blockDim.x) {
        int j  = i & 7;
        int l  = (i >> 3) & 63;
        int nt = (i >> 9) & 7;
        int kt = (i >> 12) & 7;
        int k = kt * 32 + (l >> 4) * 8 + j;
        int n = nt * 16 + (l & 15);
        bfrag[i] = __float2bfloat16(fc2_w[n * 256 + k]);
    }
}

// ---- GEMM1: h1pre = x @ W1[0:128,:] + c1 ; epilogue a_src1/a_dst1 [N,2] ----
__global__ void __launch_bounds__(128) gemm1_kernel(
        const float* __restrict__ x, const float* __restrict__ W1,
        const float* __restrict__ c1,
        const float* __restrict__ att_s, const float* __restrict__ att_d,
        float* __restrict__ h1pre, float* __restrict__ a_src, float* __restrict__ a_dst, int N) {
    __shared__ float xs[8][128];
    int tid = threadIdx.x;
    int base = blockIdx.x * 8;
    #pragma unroll
    for (int nd = 0; nd < 8; ++nd) {
        int n = base + nd;
        if (n < N) xs[nd][tid] = x[(size_t)n * 128 + tid];
    }
    __syncthreads();
    float cj = c1[tid];
    float acc[8];
    #pragma unroll
    for (int nd = 0; nd < 8; ++nd) acc[nd] = cj;
    for (int k = 0; k < 128; ++k) {
        float w = W1[k * 128 + tid];
        #pragma unroll
        for (int nd = 0; nd < 8; ++nd) acc[nd] += xs[nd][k] * w;
    }
    float asj = att_s[tid], adj = att_d[tid];
    int lane = tid & 63, h = tid >> 6;
    #pragma unroll
    for (int nd = 0; nd < 8; ++nd) {
        int n = base + nd;
        if (n >= N) break;
        h1pre[(size_t)n * 128 + tid] = acc[nd];
        float ps = wave_reduce_sum(acc[nd] * asj);
        float pd = wave_reduce_sum(acc[nd] * adj);
        if (lane == 0) { a_src[n * 2 + h] = ps; a_dst[n * 2 + h] = pd; }
    }
}

// ---- edge softmax denominator (shared by both layers) ----
__global__ void edge_softmax_kernel(const int* __restrict__ src, const int* __restrict__ dst,
                                    const float* __restrict__ a_src, const float* __restrict__ a_dst,
                                    float* __restrict__ ssum, int E) {
    int e = blockIdx.x * blockDim.x + threadIdx.x;
    if (e >= E) return;
    int s = src[e], d = dst[e];
    #pragma unroll
    for (int h = 0; h < 2; ++h) {
        float v = a_src[s * 2 + h] + a_dst[d * 2 + h];
        v = v > 0.f ? v : 0.2f * v;
        atomicAdd(&ssum[d * 2 + h], expf(v));
    }
}

// ---- layer1 aggregation: agg[dst, h*64+c] += h1pre[src, h*64+c] * alpha ----
__global__ void __launch_bounds__(256) edge_agg1_kernel(
        const int* __restrict__ src, const int* __restrict__ dst,
        const float* __restrict__ a_src, const float* __restrict__ a_dst,
        const float* __restrict__ ssum, const float* __restrict__ h1pre,
        float* __restrict__ agg, int E) {
    int e = blockIdx.x * 4 + (threadIdx.x >> 6);
    if (e >= E) return;
    int lane = threadIdx.x & 63;
    int s = src[e], d = dst[e];
    #pragma unroll
    for (int h = 0; h < 2; ++h) {
        float v = a_src[s * 2 + h] + a_dst[d * 2 + h];
        v = v > 0.f ? v : 0.2f * v;
        float alpha = expf(v) / (ssum[d * 2 + h] + 1e-16f);
        int j = h * 64 + lane;
        atomicAdd(&agg[(size_t)d * 128 + j], h1pre[(size_t)s * 128 + j] * alpha);
    }
}

// ---- elu(x + bias) in place ----
__global__ void elu_bias_kernel(float* __restrict__ a, const float* __restrict__ bias, int total) {
    int i = blockIdx.x * blockDim.x + threadIdx.x;
    if (i >= total) return;
    float v = a[i] + bias[i & 127];
    a[i] = v > 0.f ? v : expm1f(v);
}

// ---- GEMM2: h2pre = hmid @ W2 [128,256]; epilogue a_src2/a_dst2 ----
__global__ void __launch_bounds__(256) gemm2_kernel(
        const float* __restrict__ hmid, const float* __restrict__ W2,
        const float* __restrict__ att_s, const float* __restrict__ att_d,
        float* __restrict__ h2pre, float* __restrict__ a_src, float* __restrict__ a_dst, int N) {
    __shared__ float hs[8][128];
    __shared__ float red[4][8][2];
    int tid = threadIdx.x;
    int base = blockIdx.x * 8;
    for (int i = tid; i < 8 * 128; i += 256) {
        int nd = i >> 7, k = i & 127;
        int n = base + nd;
        if (n < N) hs[nd][k] = hmid[(size_t)n * 128 + k];
    }
    __syncthreads();
    float acc[8];
    #pragma unroll
    for (int nd = 0; nd < 8; ++nd) acc[nd] = 0.f;
    for (int k = 0; k < 128; ++k) {
        float w = W2[k * 256 + tid];
        #pragma unroll
        for (int nd = 0; nd < 8; ++nd) acc[nd] += hs[nd][k] * w;
    }
    float asj = att_s[tid], adj = att_d[tid];
    int lane = tid & 63, wv = tid >> 6;
    #pragma unroll
    for (int nd = 0; nd < 8; ++nd) {
        int n = base + nd;
        if (n < N) h2pre[(size_t)n * 256 + tid] = acc[nd];
        float ps = wave_reduce_sum(acc[nd] * asj);
        float pd = wave_reduce_sum(acc[nd] * adj);
        if (lane == 0) { red[wv][nd][0] = ps; red[wv][nd][1] = pd; }
    }
    __syncthreads();
    if (tid < 16) {
        int nd = tid >> 1, h = tid & 1;
        int n = base + nd;
        if (n < N) {
            a_src[n * 2 + h] = red[h * 2][nd][0] + red[h * 2 + 1][nd][0];
            a_dst[n * 2 + h] = red[h * 2][nd][1] + red[h * 2 + 1][nd][1];
        }
    }
}

// ---- layer2 aggregation with folded head-mean ----
__global__ void __launch_bounds__(256) edge_agg2_kernel(
        const int* __restrict__ src, const int* __restrict__ dst,
        const float* __restrict__ a_src, const float* __restrict__ a_dst,
        const float* __restrict__ ssum, const float* __restrict__ h2pre,
        float* __restrict__ agg, int E) {
    int e = blockIdx.x * 4 + (threadIdx.x >> 6);
    if (e >= E) return;
    int lane = threadIdx.x & 63;
    int s = src[e], d = dst[e];
    float al[2];
    #pragma unroll
    for (int h = 0; h < 2; ++h) {
        float v = a_src[s * 2 + h] + a_dst[d * 2 + h];
        v = v > 0.f ? v : 0.2f * v;
        al[h] = 0.5f * expf(v) / (ssum[d * 2 + h] + 1e-16f);
    }
    #pragma unroll
    for (int it = 0; it < 4; ++it) {
        int j = it * 64 + lane;
        int h = j >> 7;
        atomicAdd(&agg[(size_t)d * 128 + (j & 127)], h2pre[(size_t)s * 256 + j] * al[h]);
    }
}

// ---- h2bf = bf16(h2acc + bias2) : edge head reads only this ----
__global__ void bias2_bf16_kernel(const float* __restrict__ a, const float* __restrict__ bias,
                                  __hip_bfloat16* __restrict__ h2bf, int total) {
    int i = blockIdx.x * blockDim.x + threadIdx.x;
    if (i >= total) return;
    h2bf[i] = __float2bfloat16(a[i] + bias[i & 127]);
}

// ---- edge head MFMA: per wave 32 edges; A gathered from global, B from frag table ----
__global__ void __launch_bounds__(256) edge_head_mfma_kernel(
        const int* __restrict__ src, const int* __restrict__ dst,
        const __hip_bfloat16* __restrict__ h2bf,
        const __hip_bfloat16* __restrict__ bfrag,
        const float* __restrict__ fc2_b, const float* __restrict__ fc3_w,
        const float* __restrict__ fc3_b, float* __restrict__ out, int E) {
    int lane = threadIdx.x & 63;
    int wv   = threadIdx.x >> 6;
    int lo = lane & 15, quad = lane >> 4;
    long base = ((long)blockIdx.x * 4 + wv) * 32;
    if (base >= E) return;  // wave-uniform
    int e0 = (int)base + lo;
    int e1 = (int)base + 16 + lo;
    int e0c = e0 < E ? e0 : E - 1;
    int e1c = e1 < E ? e1 : E - 1;
    // A rows: edge m-index = lane&15 ; k half selects src vs dst row
    const __hip_bfloat16* r0s = h2bf + (size_t)src[e0c] * 128;
    const __hip_bfloat16* r0d = h2bf + (size_t)dst[e0c] * 128;
    const __hip_bfloat16* r1s = h2bf + (size_t)src[e1c] * 128;
    const __hip_bfloat16* r1d = h2bf + (size_t)dst[e1c] * 128;

    floatx4 acc[2][8];
    #pragma unroll
    for (int mb = 0; mb < 2; ++mb)
        #pragma unroll
        for (int nt = 0; nt < 8; ++nt) acc[mb][nt] = (floatx4){0.f, 0.f, 0.f, 0.f};

    const short8* bf = (const short8*)bfrag;
    #pragma unroll
    for (int kt = 0; kt < 8; ++kt) {
        int k = kt * 32 + quad * 8;  // this lane's 8 contiguous K elements
        const short8* p0 = (const short8*)(k < 128 ? r0s + k : r0d + (k - 128));
        const short8* p1 = (const short8*)(k < 128 ? r1s + k : r1d + (k - 128));
        short8 a0 = *p0;
        short8 a1 = *p1;
        #pragma unroll
        for (int nt = 0; nt < 8; ++nt) {
            short8 b = bf[(kt * 8 + nt) * 64 + lane];
            acc[0][nt] = __builtin_amdgcn_mfma_f32_16x16x32_bf16(a0, b, acc[0][nt], 0, 0, 0);
            acc[1][nt] = __builtin_amdgcn_mfma_f32_16x16x32_bf16(a1, b, acc[1][nt], 0, 0, 0);
        }
    }
    // epilogue: z = relu(D + fc2_b); logit = z . fc3_w ; D layout: col=lane&15, row=quad*4+reg
    float fb[8], f3[8];
    #pragma unroll
    for (int nt = 0; nt < 8; ++nt) {
        fb[nt] = fc2_b[nt * 16 + lo];
        f3[nt] = fc3_w[nt * 16 + lo];
    }
    float b3 = fc3_b[0];
    #pragma unroll
    for (int mb = 0; mb < 2; ++mb) {
        #pragma unroll
        for (int r = 0; r < 4; ++r) {
            float p = 0.f;
            #pragma unroll
            for (int nt = 0; nt < 8; ++nt)
                p += fmaxf(acc[mb][nt][r] + fb[nt], 0.f) * f3[nt];
            p += __shfl_xor(p, 1, 64);
            p += __shfl_xor(p, 2, 64);
            p += __shfl_xor(p, 4, 64);
            p += __shfl_xor(p, 8, 64);
            int e = (int)base + mb * 16 + quad * 4 + r;
            if (lo == 0 && e < E)
                out[e] = 1.f / (1.f + expf(-(p + b3)));
        }
    }
}

extern "C" void kernel_launch(void* const* d_in, const int* in_sizes, int n_in,
                              void* d_out, int out_size, void* d_ws, size_t ws_size,
                              hipStream_t stream) {
    const float* x      = (const float*)d_in[0];
    const int*   ei     = (const int*)d_in[1];
    const float* cls    = (const float*)d_in[2];
    const float* fc0_w  = (const float*)d_in[3];
    const float* fc0_b  = (const float*)d_in[4];
    const float* W1     = (const float*)d_in[5];
    const float* att_s1 = (const float*)d_in[6];
    const float* att_d1 = (const float*)d_in[7];
    const float* bias1  = (const float*)d_in[8];
    const float* W2     = (const float*)d_in[9];
    const float* att_s2 = (const float*)d_in[10];
    const float* att_d2 = (const float*)d_in[11];
    const float* bias2  = (const float*)d_in[12];
    const float* fc2_w  = (const float*)d_in[13];
    const float* fc2_b  = (const float*)d_in[14];
    const float* fc3_w  = (const float*)d_in[15];
    const float* fc3_b  = (const float*)d_in[16];
    float* out = (float*)d_out;

    int N = in_sizes[0] / 128;
    int E = in_sizes[1] / 2;
    const int* src = ei;
    const int* dst = ei + E;

    float* w = (float*)d_ws;
    size_t off = 0;
    auto alloc = [&](size_t n) { float* p = w + off; off += (n + 63) & ~(size_t)63; return p; };
    float* c1    = alloc(128);
    float* bfragf= alloc(8 * 8 * 64 * 8 / 2);      // 32768 bf16 = 16384 floats
    float* a_s1  = alloc((size_t)N * 2);
    float* a_d1  = alloc((size_t)N * 2);
    float* a_s2  = alloc((size_t)N * 2);
    float* a_d2  = alloc((size_t)N * 2);
    float* s1    = alloc((size_t)N * 2);
    float* s2    = alloc((size_t)N * 2);
    float* h1pre = alloc((size_t)N * 128);  // later reused as h2 accumulator
    float* agg1  = alloc((size_t)N * 128);  // becomes hmid (ELU in place)
    float* h2pre = alloc((size_t)N * 256);
    float* h2bff = alloc((size_t)N * 64);   // N*128 bf16
    __hip_bfloat16* bfrag = (__hip_bfloat16*)bfragf;
    __hip_bfloat16* h2bf  = (__hip_bfloat16*)h2bff;

    hipMemsetAsync(s1, 0, sizeof(float) * (size_t)N * 2, stream);
    hipMemsetAsync(s2, 0, sizeof(float) * (size_t)N * 2, stream);
    hipMemsetAsync(agg1, 0, sizeof(float) * (size_t)N * 128, stream);

    prep_kernel<<<1, 256, 0, stream>>>(cls, fc0_w, fc0_b, W1, fc2_w, c1, bfrag);
    gemm1_kernel<<<(N + 7) / 8, 128, 0, stream>>>(x, W1, c1, att_s1, att_d1, h1pre, a_s1, a_d1, N);
    edge_softmax_kernel<<<(E + 255) / 256, 256, 0, stream>>>(src, dst, a_s1, a_d1, s1, E);
    edge_agg1_kernel<<<(E + 3) / 4, 256, 0, stream>>>(src, dst, a_s1, a_d1, s1, h1pre, agg1, E);
    elu_bias_kernel<<<(N * 128 + 255) / 256, 256, 0, stream>>>(agg1, bias1, N * 128);
    // h1pre is dead now -> reuse as layer-2 accumulator
    hipMemsetAsync(h1pre, 0, sizeof(float) * (size_t)N * 128, stream);
    gemm2_kernel<<<(N + 7) / 8, 256, 0, stream>>>(agg1, W2, att_s2, att_d2, h2pre, a_s2, a_d2, N);
    edge_softmax_kernel<<<(E + 255) / 256, 256, 0, stream>>>(src, dst, a_s2, a_d2, s2, E);
    edge_agg2_kernel<<<(E + 3) / 4, 256, 0, stream>>>(src, dst, a_s2, a_d2, s2, h2pre, h1pre, E);
    bias2_bf16_kernel<<<(N * 128 + 255) / 256, 256, 0, stream>>>(h1pre, bias2, h2bf, N * 128);
    edge_head_mfma_kernel<<<(E + 127) / 128, 256, 0, stream>>>(src, dst, h2bf, bfrag, fc2_b, fc3_w, fc3_b, out, E);
}

// Round 3
// 604.795 us; speedup vs baseline: 3.0557x; 1.9244x over previous
//
#include <hip/hip_runtime.h>
#include <hip/hip_bf16.h>
#include <math.h>

// N=50000, E=500000, SED=128, HID=64, H=2, F_node=128
// Round 3: dst-CSR build + wave-per-dst fused softmax/aggregate (no atomics on
// feature vectors), h2pre stored bf16, edge head stays MFMA bf16 gather-GEMM.

typedef short short8 __attribute__((ext_vector_type(8)));
typedef float floatx4 __attribute__((ext_vector_type(4)));

__device__ __forceinline__ float wave_reduce_sum(float v) {
    #pragma unroll
    for (int off = 32; off > 0; off >>= 1) v += __shfl_down(v, off, 64);
    return v;
}
__device__ __forceinline__ float wave_allreduce_sum(float v) {
    #pragma unroll
    for (int off = 1; off < 64; off <<= 1) v += __shfl_xor(v, off, 64);
    return v;
}
__device__ __forceinline__ float bf16lo(unsigned u) {
    unsigned x = u << 16; return __builtin_bit_cast(float, x);
}
__device__ __forceinline__ float bf16hi(unsigned u) {
    unsigned x = u & 0xFFFF0000u; return __builtin_bit_cast(float, x);
}

// ---- tiny precompute: sent vec, c1 (sent contribution through W1), fc2 B-fragment table ----
__global__ void prep_kernel(const float* __restrict__ cls, const float* __restrict__ fc0_w,
                            const float* __restrict__ fc0_b, const float* __restrict__ W1,
                            const float* __restrict__ fc2_w,
                            float* __restrict__ c1, __hip_bfloat16* __restrict__ bfrag) {
    __shared__ float s_sent[128];
    int tid = threadIdx.x;
    if (tid < 128) {
        float acc = fc0_b[tid];
        const float* row = fc0_w + (size_t)tid * 768;
        for (int k = 0; k < 768; ++k) acc += row[k] * cls[k];
        s_sent[tid] = acc;
    }
    __syncthreads();
    if (tid < 128) {
        float acc = 0.f;
        for (int k = 0; k < 128; ++k) acc += s_sent[k] * W1[(128 + k) * 128 + tid];
        c1[tid] = acc;
    }
    // B-frag for mfma_f32_16x16x32_bf16: B[k][n], k=kt*32+(lane>>4)*8+j, n=nt*16+(lane&15)
    for (int i = tid; i < 8 * 8 * 64 * 8; i += blockDim.x) {
        int j  = i & 7;
        int l  = (i >> 3) & 63;
        int nt = (i >> 9) & 7;
        int kt = (i >> 12) & 7;
        int k = kt * 32 + (l >> 4) * 8 + j;
        int n = nt * 16 + (l & 15);
        bfrag[i] = __float2bfloat16(fc2_w[n * 256 + k]);
    }
}

// ---- CSR build ----
__global__ void count_kernel(const int* __restrict__ dst, int* __restrict__ counts, int E) {
    int e = blockIdx.x * blockDim.x + threadIdx.x;
    if (e < E) atomicAdd(&counts[dst[e]], 1);
}

__global__ void __launch_bounds__(1024) scan_kernel(const int* __restrict__ counts,
                                                    int* __restrict__ row, int* __restrict__ woff,
                                                    int N, int E) {
    int tid = threadIdx.x, lane = tid & 63, wv = tid >> 6;
    __shared__ int wsum[16];
    __shared__ int carry;
    if (tid == 0) carry = 0;
    __syncthreads();
    for (int base = 0; base < N; base += 1024) {
        int v = (base + tid < N) ? counts[base + tid] : 0;
        int x = v;
        #pragma unroll
        for (int off = 1; off < 64; off <<= 1) {
            int t = __shfl_up(x, off, 64);
            if (lane >= off) x += t;
        }
        if (lane == 63) wsum[wv] = x;
        __syncthreads();
        if (wv == 0 && lane < 16) {
            int y = wsum[lane];
            #pragma unroll
            for (int off = 1; off < 16; off <<= 1) {
                int t = __shfl_up(y, off, 64);
                if (lane >= off) y += t;
            }
            wsum[lane] = y;
        }
        __syncthreads();
        int wexcl = (wv == 0) ? 0 : wsum[wv - 1];
        int excl = carry + wexcl + x - v;
        if (base + tid < N) { row[base + tid] = excl; woff[base + tid] = excl; }
        __syncthreads();
        if (tid == 0) carry += wsum[15];
        __syncthreads();
    }
    if (tid == 0) row[N] = E;
}

__global__ void scatter_kernel(const int* __restrict__ dst, int* __restrict__ woff,
                               int* __restrict__ eid, int E) {
    int e = blockIdx.x * blockDim.x + threadIdx.x;
    if (e < E) {
        int pos = atomicAdd(&woff[dst[e]], 1);
        eid[pos] = e;
    }
}

// ---- GEMM1: h1pre = x @ W1[0:128,:] + c1 ; epilogue a_src1/a_dst1 [N,2] ----
__global__ void __launch_bounds__(128) gemm1_kernel(
        const float* __restrict__ x, const float* __restrict__ W1,
        const float* __restrict__ c1,
        const float* __restrict__ att_s, const float* __restrict__ att_d,
        float* __restrict__ h1pre, float* __restrict__ a_src, float* __restrict__ a_dst, int N) {
    __shared__ float xs[8][128];
    int tid = threadIdx.x;
    int base = blockIdx.x * 8;
    #pragma unroll
    for (int nd = 0; nd < 8; ++nd) {
        int n = base + nd;
        if (n < N) xs[nd][tid] = x[(size_t)n * 128 + tid];
    }
    __syncthreads();
    float cj = c1[tid];
    float acc[8];
    #pragma unroll
    for (int nd = 0; nd < 8; ++nd) acc[nd] = cj;
    for (int k = 0; k < 128; ++k) {
        float w = W1[k * 128 + tid];
        #pragma unroll
        for (int nd = 0; nd < 8; ++nd) acc[nd] += xs[nd][k] * w;
    }
    float asj = att_s[tid], adj = att_d[tid];
    int lane = tid & 63, h = tid >> 6;
    #pragma unroll
    for (int nd = 0; nd < 8; ++nd) {
        int n = base + nd;
        if (n >= N) break;
        h1pre[(size_t)n * 128 + tid] = acc[nd];
        float ps = wave_reduce_sum(acc[nd] * asj);
        float pd = wave_reduce_sum(acc[nd] * adj);
        if (lane == 0) { a_src[n * 2 + h] = ps; a_dst[n * 2 + h] = pd; }
    }
}

// ---- agg1: wave per dst; fused softmax + gather-agg + bias + ELU -> hmid ----
__global__ void __launch_bounds__(256) agg1_csr_kernel(
        const int* __restrict__ row, const int* __restrict__ eid, const int* __restrict__ src,
        const float* __restrict__ a_src, const float* __restrict__ a_dst,
        const float* __restrict__ h1pre, const float* __restrict__ bias1,
        float* __restrict__ hmid, int N) {
    int d = blockIdx.x * 4 + (threadIdx.x >> 6);
    if (d >= N) return;
    int lane = threadIdx.x & 63;
    int beg = row[d], end = row[d + 1];
    float ad0 = a_dst[d * 2 + 0], ad1 = a_dst[d * 2 + 1];
    // pass 1: denominators
    float den0 = 0.f, den1 = 0.f;
    for (int b = beg; b < end; b += 64) {
        int i = b + lane;
        if (i < end) {
            int s = src[eid[i]];
            float v0 = a_src[s * 2 + 0] + ad0; v0 = v0 > 0.f ? v0 : 0.2f * v0;
            float v1 = a_src[s * 2 + 1] + ad1; v1 = v1 > 0.f ? v1 : 0.2f * v1;
            den0 += __expf(v0);
            den1 += __expf(v1);
        }
    }
    den0 = wave_allreduce_sum(den0);
    den1 = wave_allreduce_sum(den1);
    float inv0 = 1.f / (den0 + 1e-16f);
    float inv1 = 1.f / (den1 + 1e-16f);
    // pass 2: broadcast alpha, gather h1pre[src]
    float acc0 = 0.f, acc1 = 0.f;  // channels lane (head0), 64+lane (head1)
    for (int b = beg; b < end; b += 64) {
        int cnt = min(64, end - b);
        int i = b + lane;
        int s = 0; float ex0 = 0.f, ex1 = 0.f;
        if (i < end) {
            s = src[eid[i]];
            float v0 = a_src[s * 2 + 0] + ad0; v0 = v0 > 0.f ? v0 : 0.2f * v0;
            float v1 = a_src[s * 2 + 1] + ad1; v1 = v1 > 0.f ? v1 : 0.2f * v1;
            ex0 = __expf(v0); ex1 = __expf(v1);
        }
        for (int j = 0; j < cnt; ++j) {
            float al0 = __shfl(ex0, j, 64) * inv0;
            float al1 = __shfl(ex1, j, 64) * inv1;
            int sj = __shfl(s, j, 64);
            const float* rp = h1pre + (size_t)sj * 128;
            acc0 += rp[lane] * al0;
            acc1 += rp[64 + lane] * al1;
        }
    }
    float v0 = acc0 + bias1[lane];
    float v1 = acc1 + bias1[64 + lane];
    hmid[(size_t)d * 128 + lane]      = v0 > 0.f ? v0 : expm1f(v0);
    hmid[(size_t)d * 128 + 64 + lane] = v1 > 0.f ? v1 : expm1f(v1);
}

// ---- GEMM2: h2pre(bf16) = hmid @ W2 [128,256]; epilogue a_src2/a_dst2 ----
__global__ void __launch_bounds__(256) gemm2_kernel(
        const float* __restrict__ hmid, const float* __restrict__ W2,
        const float* __restrict__ att_s, const float* __restrict__ att_d,
        __hip_bfloat16* __restrict__ h2pre, float* __restrict__ a_src, float* __restrict__ a_dst, int N) {
    __shared__ float hs[8][128];
    __shared__ float red[4][8][2];
    int tid = threadIdx.x;
    int base = blockIdx.x * 8;
    for (int i = tid; i < 8 * 128; i += 256) {
        int nd = i >> 7, k = i & 127;
        int n = base + nd;
        if (n < N) hs[nd][k] = hmid[(size_t)n * 128 + k];
    }
    __syncthreads();
    float acc[8];
    #pragma unroll
    for (int nd = 0; nd < 8; ++nd) acc[nd] = 0.f;
    for (int k = 0; k < 128; ++k) {
        float w = W2[k * 256 + tid];
        #pragma unroll
        for (int nd = 0; nd < 8; ++nd) acc[nd] += hs[nd][k] * w;
    }
    float asj = att_s[tid], adj = att_d[tid];
    int lane = tid & 63, wv = tid >> 6;
    #pragma unroll
    for (int nd = 0; nd < 8; ++nd) {
        int n = base + nd;
        if (n < N) h2pre[(size_t)n * 256 + tid] = __float2bfloat16(acc[nd]);
        float ps = wave_reduce_sum(acc[nd] * asj);
        float pd = wave_reduce_sum(acc[nd] * adj);
        if (lane == 0) { red[wv][nd][0] = ps; red[wv][nd][1] = pd; }
    }
    __syncthreads();
    if (tid < 16) {
        int nd = tid >> 1, h = tid & 1;
        int n = base + nd;
        if (n < N) {
            a_src[n * 2 + h] = red[h * 2][nd][0] + red[h * 2 + 1][nd][0];
            a_dst[n * 2 + h] = red[h * 2][nd][1] + red[h * 2 + 1][nd][1];
        }
    }
}

// ---- agg2: wave per dst; fused softmax + bf16 gather + head-mean + bias -> h2bf ----
__global__ void __launch_bounds__(256) agg2_csr_kernel(
        const int* __restrict__ row, const int* __restrict__ eid, const int* __restrict__ src,
        const float* __restrict__ a_src, const float* __restrict__ a_dst,
        const __hip_bfloat16* __restrict__ h2pre, const float* __restrict__ bias2,
        __hip_bfloat16* __restrict__ h2bf, int N) {
    int d = blockIdx.x * 4 + (threadIdx.x >> 6);
    if (d >= N) return;
    int lane = threadIdx.x & 63;
    int beg = row[d], end = row[d + 1];
    float ad0 = a_dst[d * 2 + 0], ad1 = a_dst[d * 2 + 1];
    float den0 = 0.f, den1 = 0.f;
    for (int b = beg; b < end; b += 64) {
        int i = b + lane;
        if (i < end) {
            int s = src[eid[i]];
            float v0 = a_src[s * 2 + 0] + ad0; v0 = v0 > 0.f ? v0 : 0.2f * v0;
            float v1 = a_src[s * 2 + 1] + ad1; v1 = v1 > 0.f ? v1 : 0.2f * v1;
            den0 += __expf(v0);
            den1 += __expf(v1);
        }
    }
    den0 = wave_allreduce_sum(den0);
    den1 = wave_allreduce_sum(den1);
    float inv0 = 0.5f / (den0 + 1e-16f);   // fold head-mean 0.5
    float inv1 = 0.5f / (den1 + 1e-16f);
    const unsigned* h2u = (const unsigned*)h2pre;  // pairs of bf16 channels
    float accA = 0.f, accB = 0.f;  // channels 2*lane, 2*lane+1
    for (int b = beg; b < end; b += 64) {
        int cnt = min(64, end - b);
        int i = b + lane;
        int s = 0; float ex0 = 0.f, ex1 = 0.f;
        if (i < end) {
            s = src[eid[i]];
            float v0 = a_src[s * 2 + 0] + ad0; v0 = v0 > 0.f ? v0 : 0.2f * v0;
            float v1 = a_src[s * 2 + 1] + ad1; v1 = v1 > 0.f ? v1 : 0.2f * v1;
            ex0 = __expf(v0); ex1 = __expf(v1);
        }
        for (int j = 0; j < cnt; ++j) {
            float al0 = __shfl(ex0, j, 64) * inv0;
            float al1 = __shfl(ex1, j, 64) * inv1;
            int sj = __shfl(s, j, 64);
            unsigned u0 = h2u[(size_t)sj * 128 + lane];        // head0, ch 2lane,2lane+1
            unsigned u1 = h2u[(size_t)sj * 128 + 64 + lane];   // head1, ch 2lane,2lane+1
            accA += bf16lo(u0) * al0 + bf16lo(u1) * al1;
            accB += bf16hi(u0) * al0 + bf16hi(u1) * al1;
        }
    }
    int c = 2 * lane;
    __hip_bfloat16 oa = __float2bfloat16(accA + bias2[c]);
    __hip_bfloat16 ob = __float2bfloat16(accB + bias2[c + 1]);
    unsigned pack = ((unsigned)__builtin_bit_cast(unsigned short, ob) << 16) |
                    (unsigned)__builtin_bit_cast(unsigned short, oa);
    ((unsigned*)h2bf)[(size_t)d * 64 + lane] = pack;
}

// ---- edge head MFMA: per wave 32 edges; A gathered from global, B from frag table ----
__global__ void __launch_bounds__(256) edge_head_mfma_kernel(
        const int* __restrict__ src, const int* __restrict__ dst,
        const __hip_bfloat16* __restrict__ h2bf,
        const __hip_bfloat16* __restrict__ bfrag,
        const float* __restrict__ fc2_b, const float* __restrict__ fc3_w,
        const float* __restrict__ fc3_b, float* __restrict__ out, int E) {
    int lane = threadIdx.x & 63;
    int wv   = threadIdx.x >> 6;
    int lo = lane & 15, quad = lane >> 4;
    long base = ((long)blockIdx.x * 4 + wv) * 32;
    if (base >= E) return;  // wave-uniform
    int e0 = (int)base + lo;
    int e1 = (int)base + 16 + lo;
    int e0c = e0 < E ? e0 : E - 1;
    int e1c = e1 < E ? e1 : E - 1;
    const __hip_bfloat16* r0s = h2bf + (size_t)src[e0c] * 128;
    const __hip_bfloat16* r0d = h2bf + (size_t)dst[e0c] * 128;
    const __hip_bfloat16* r1s = h2bf + (size_t)src[e1c] * 128;
    const __hip_bfloat16* r1d = h2bf + (size_t)dst[e1c] * 128;

    floatx4 acc[2][8];
    #pragma unroll
    for (int mb = 0; mb < 2; ++mb)
        #pragma unroll
        for (int nt = 0; nt < 8; ++nt) acc[mb][nt] = (floatx4){0.f, 0.f, 0.f, 0.f};

    const short8* bf = (const short8*)bfrag;
    #pragma unroll
    for (int kt = 0; kt < 8; ++kt) {
        int k = kt * 32 + quad * 8;
        const short8* p0 = (const short8*)(k < 128 ? r0s + k : r0d + (k - 128));
        const short8* p1 = (const short8*)(k < 128 ? r1s + k : r1d + (k - 128));
        short8 a0 = *p0;
        short8 a1 = *p1;
        #pragma unroll
        for (int nt = 0; nt < 8; ++nt) {
            short8 b = bf[(kt * 8 + nt) * 64 + lane];
            acc[0][nt] = __builtin_amdgcn_mfma_f32_16x16x32_bf16(a0, b, acc[0][nt], 0, 0, 0);
            acc[1][nt] = __builtin_amdgcn_mfma_f32_16x16x32_bf16(a1, b, acc[1][nt], 0, 0, 0);
        }
    }
    float fb[8], f3[8];
    #pragma unroll
    for (int nt = 0; nt < 8; ++nt) {
        fb[nt] = fc2_b[nt * 16 + lo];
        f3[nt] = fc3_w[nt * 16 + lo];
    }
    float b3 = fc3_b[0];
    #pragma unroll
    for (int mb = 0; mb < 2; ++mb) {
        #pragma unroll
        for (int r = 0; r < 4; ++r) {
            float p = 0.f;
            #pragma unroll
            for (int nt = 0; nt < 8; ++nt)
                p += fmaxf(acc[mb][nt][r] + fb[nt], 0.f) * f3[nt];
            p += __shfl_xor(p, 1, 64);
            p += __shfl_xor(p, 2, 64);
            p += __shfl_xor(p, 4, 64);
            p += __shfl_xor(p, 8, 64);
            int e = (int)base + mb * 16 + quad * 4 + r;
            if (lo == 0 && e < E)
                out[e] = 1.f / (1.f + expf(-(p + b3)));
        }
    }
}

extern "C" void kernel_launch(void* const* d_in, const int* in_sizes, int n_in,
                              void* d_out, int out_size, void* d_ws, size_t ws_size,
                              hipStream_t stream) {
    const float* x      = (const float*)d_in[0];
    const int*   ei     = (const int*)d_in[1];
    const float* cls    = (const float*)d_in[2];
    const float* fc0_w  = (const float*)d_in[3];
    const float* fc0_b  = (const float*)d_in[4];
    const float* W1     = (const float*)d_in[5];
    const float* att_s1 = (const float*)d_in[6];
    const float* att_d1 = (const float*)d_in[7];
    const float* bias1  = (const float*)d_in[8];
    const float* W2     = (const float*)d_in[9];
    const float* att_s2 = (const float*)d_in[10];
    const float* att_d2 = (const float*)d_in[11];
    const float* bias2  = (const float*)d_in[12];
    const float* fc2_w  = (const float*)d_in[13];
    const float* fc2_b  = (const float*)d_in[14];
    const float* fc3_w  = (const float*)d_in[15];
    const float* fc3_b  = (const float*)d_in[16];
    float* out = (float*)d_out;

    int N = in_sizes[0] / 128;
    int E = in_sizes[1] / 2;
    const int* src = ei;
    const int* dst = ei + E;

    float* w = (float*)d_ws;
    size_t off = 0;
    auto alloc = [&](size_t n) { float* p = w + off; off += (n + 63) & ~(size_t)63; return p; };
    float* c1     = alloc(128);
    float* bfragf = alloc(8 * 8 * 64 * 8 / 2);
    float* a_s1   = alloc((size_t)N * 2);
    float* a_d1   = alloc((size_t)N * 2);
    float* a_s2   = alloc((size_t)N * 2);
    float* a_d2   = alloc((size_t)N * 2);
    float* h1pre  = alloc((size_t)N * 128);
    float* hmid   = alloc((size_t)N * 128);
    float* h2pref = alloc((size_t)N * 128);  // N*256 bf16
    float* h2bff  = alloc((size_t)N * 64);   // N*128 bf16
    int* counts = (int*)alloc(N);
    int* rowp   = (int*)alloc(N + 1);
    int* woff   = (int*)alloc(N);
    int* eidb   = (int*)alloc(E);
    __hip_bfloat16* bfrag = (__hip_bfloat16*)bfragf;
    __hip_bfloat16* h2pre = (__hip_bfloat16*)h2pref;
    __hip_bfloat16* h2bf  = (__hip_bfloat16*)h2bff;

    hipMemsetAsync(counts, 0, sizeof(int) * (size_t)N, stream);

    prep_kernel<<<1, 256, 0, stream>>>(cls, fc0_w, fc0_b, W1, fc2_w, c1, bfrag);
    count_kernel<<<(E + 255) / 256, 256, 0, stream>>>(dst, counts, E);
    scan_kernel<<<1, 1024, 0, stream>>>(counts, rowp, woff, N, E);
    scatter_kernel<<<(E + 255) / 256, 256, 0, stream>>>(dst, woff, eidb, E);
    gemm1_kernel<<<(N + 7) / 8, 128, 0, stream>>>(x, W1, c1, att_s1, att_d1, h1pre, a_s1, a_d1, N);
    agg1_csr_kernel<<<(N + 3) / 4, 256, 0, stream>>>(rowp, eidb, src, a_s1, a_d1, h1pre, bias1, hmid, N);
    gemm2_kernel<<<(N + 7) / 8, 256, 0, stream>>>(hmid, W2, att_s2, att_d2, h2pre, a_s2, a_d2, N);
    agg2_csr_kernel<<<(N + 3) / 4, 256, 0, stream>>>(rowp, eidb, src, a_s2, a_d2, h2pre, bias2, h2bf, N);
    edge_head_mfma_kernel<<<(E + 127) / 128, 256, 0, stream>>>(src, dst, h2bf, bfrag, fc2_b, fc3_w, fc3_b, out, E);
}

// Round 4
// 448.195 us; speedup vs baseline: 4.1233x; 1.3494x over previous
//
#include <hip/hip_runtime.h>
#include <hip/hip_bf16.h>
#include <math.h>

// N=50000, E=500000, SED=128, HID=64, H=2, F_node=128
// Round 4: all node GEMMs on MFMA bf16 (LDS-free, 16 rows/wave, frag tables);
// edge head rewritten algebraically: zs/zd per-node precompute, per-edge
// sigmoid(fc3 . relu(zs[src]+zd[dst])). CSR agg kernels gather bf16.

typedef short short8 __attribute__((ext_vector_type(8)));
typedef float floatx4 __attribute__((ext_vector_type(4)));

__device__ __forceinline__ float wave_allreduce_sum(float v) {
    #pragma unroll
    for (int off = 1; off < 64; off <<= 1) v += __shfl_xor(v, off, 64);
    return v;
}
__device__ __forceinline__ float bf16lo(unsigned u) {
    unsigned x = u << 16; return __builtin_bit_cast(float, x);
}
__device__ __forceinline__ float bf16hi(unsigned u) {
    unsigned x = u & 0xFFFF0000u; return __builtin_bit_cast(float, x);
}
__device__ __forceinline__ unsigned short bfbits(float f) {
    return __builtin_bit_cast(unsigned short, __float2bfloat16(f));
}

// ---- prep: sent/c1; bf16 B-fragment tables for W1, W2, fc2(split) ----
// frag layout for mfma_f32_16x16x32_bf16 B: B[k][n], k=kt*32+(lane>>4)*8+j,
// n=nt*16+(lane&15); idx = ((kt*NT+nt)*64+lane)*8+j
__global__ void prep_kernel(const float* __restrict__ cls, const float* __restrict__ fc0_w,
                            const float* __restrict__ fc0_b, const float* __restrict__ W1,
                            const float* __restrict__ W2, const float* __restrict__ fc2_w,
                            float* __restrict__ c1,
                            __hip_bfloat16* __restrict__ w1frag,
                            __hip_bfloat16* __restrict__ w2frag,
                            __hip_bfloat16* __restrict__ fc2frag) {
    int tid = threadIdx.x;
    if (blockIdx.x == 0) {
        __shared__ float s_sent[128];
        if (tid < 128) {
            float acc = fc0_b[tid];
            const float* row = fc0_w + (size_t)tid * 768;
            for (int k = 0; k < 768; ++k) acc += row[k] * cls[k];
            s_sent[tid] = acc;
        }
        __syncthreads();
        if (tid < 128) {
            float acc = 0.f;
            for (int k = 0; k < 128; ++k) acc += s_sent[k] * W1[(128 + k) * 128 + tid];
            c1[tid] = acc;
        }
    }
    int gstride = gridDim.x * blockDim.x;
    int g = blockIdx.x * blockDim.x + tid;
    // W1frag: NT=8 (N=128), KT=4 (K=128): 4*8*64*8 = 16384
    for (int i = g; i < 16384; i += gstride) {
        int j = i & 7, l = (i >> 3) & 63, nt = (i >> 9) & 7, kt = (i >> 12) & 3;
        int k = kt * 32 + (l >> 4) * 8 + j;
        int n = nt * 16 + (l & 15);
        w1frag[i] = __float2bfloat16(W1[k * 128 + n]);
    }
    // W2frag: NT=16 (N=256), KT=4: 4*16*64*8 = 32768
    for (int i = g; i < 32768; i += gstride) {
        int j = i & 7, l = (i >> 3) & 63, nt = (i >> 9) & 15, kt = (i >> 13) & 3;
        int k = kt * 32 + (l >> 4) * 8 + j;
        int n = nt * 16 + (l & 15);
        w2frag[i] = __float2bfloat16(W2[k * 256 + n]);
    }
    // fc2frag: NT=16: n<128 -> zs = fc2_w[n][k]; n>=128 -> zd = fc2_w[n-128][128+k]
    for (int i = g; i < 32768; i += gstride) {
        int j = i & 7, l = (i >> 3) & 63, nt = (i >> 9) & 15, kt = (i >> 13) & 3;
        int k = kt * 32 + (l >> 4) * 8 + j;
        int n = nt * 16 + (l & 15);
        float v = (n < 128) ? fc2_w[n * 256 + k] : fc2_w[(n - 128) * 256 + 128 + k];
        fc2frag[i] = __float2bfloat16(v);
    }
}

// ---- CSR build ----
__global__ void count_kernel(const int* __restrict__ dst, int* __restrict__ counts, int E) {
    int e = blockIdx.x * blockDim.x + threadIdx.x;
    if (e < E) atomicAdd(&counts[dst[e]], 1);
}

__global__ void __launch_bounds__(1024) scan_kernel(const int* __restrict__ counts,
                                                    int* __restrict__ row, int* __restrict__ woff,
                                                    int N, int E) {
    int tid = threadIdx.x, lane = tid & 63, wv = tid >> 6;
    __shared__ int wsum[16];
    __shared__ int carry;
    if (tid == 0) carry = 0;
    __syncthreads();
    for (int base = 0; base < N; base += 1024) {
        int v = (base + tid < N) ? counts[base + tid] : 0;
        int x = v;
        #pragma unroll
        for (int off = 1; off < 64; off <<= 1) {
            int t = __shfl_up(x, off, 64);
            if (lane >= off) x += t;
        }
        if (lane == 63) wsum[wv] = x;
        __syncthreads();
        if (wv == 0 && lane < 16) {
            int y = wsum[lane];
            #pragma unroll
            for (int off = 1; off < 16; off <<= 1) {
                int t = __shfl_up(y, off, 64);
                if (lane >= off) y += t;
            }
            wsum[lane] = y;
        }
        __syncthreads();
        int wexcl = (wv == 0) ? 0 : wsum[wv - 1];
        int excl = carry + wexcl + x - v;
        if (base + tid < N) { row[base + tid] = excl; woff[base + tid] = excl; }
        __syncthreads();
        if (tid == 0) carry += wsum[15];
        __syncthreads();
    }
    if (tid == 0) row[N] = E;
}

__global__ void scatter_kernel(const int* __restrict__ dst, int* __restrict__ woff,
                               int* __restrict__ eid, int E) {
    int e = blockIdx.x * blockDim.x + threadIdx.x;
    if (e < E) {
        int pos = atomicAdd(&woff[dst[e]], 1);
        eid[pos] = e;
    }
}

// ---- x fp32 -> bf16 packed ----
__global__ void cvt_bf16_kernel(const float* __restrict__ in, unsigned* __restrict__ outu, int n2) {
    int i = blockIdx.x * blockDim.x + threadIdx.x;
    if (i >= n2) return;
    float a = in[2 * i], b = in[2 * i + 1];
    outu[i] = ((unsigned)bfbits(b) << 16) | (unsigned)bfbits(a);
}

// ---- gemm1 MFMA: h1bf[N,128](bf16) = xbf @ W1frag + c1 ; logits a_s1/a_d1 ----
__global__ void __launch_bounds__(256) gemm1_mfma_kernel(
        const __hip_bfloat16* __restrict__ xbf, const __hip_bfloat16* __restrict__ wfrag,
        const float* __restrict__ c1, const float* __restrict__ att_s, const float* __restrict__ att_d,
        __hip_bfloat16* __restrict__ h1bf, float* __restrict__ a_src, float* __restrict__ a_dst, int N) {
    int lane = threadIdx.x & 63, wv = threadIdx.x >> 6;
    int lo = lane & 15, quad = lane >> 4;
    int rowbase = (blockIdx.x * 4 + wv) * 16;
    if (rowbase >= N) return;
    int arow = rowbase + lo; if (arow >= N) arow = N - 1;
    const __hip_bfloat16* ap = xbf + (size_t)arow * 128 + quad * 8;
    floatx4 acc[8];
    #pragma unroll
    for (int nt = 0; nt < 8; ++nt) acc[nt] = (floatx4){0.f, 0.f, 0.f, 0.f};
    const short8* bf = (const short8*)wfrag;
    #pragma unroll
    for (int kt = 0; kt < 4; ++kt) {
        short8 a = *(const short8*)(ap + kt * 32);
        #pragma unroll
        for (int nt = 0; nt < 8; ++nt)
            acc[nt] = __builtin_amdgcn_mfma_f32_16x16x32_bf16(a, bf[(kt * 8 + nt) * 64 + lane], acc[nt], 0, 0, 0);
    }
    // epilogue: D row = rowbase + quad*4 + r, ch = nt*16 + lo
    float ps0[4] = {0,0,0,0}, ps1[4] = {0,0,0,0}, pd0[4] = {0,0,0,0}, pd1[4] = {0,0,0,0};
    #pragma unroll
    for (int nt = 0; nt < 8; ++nt) {
        int ch = nt * 16 + lo;
        float cv = c1[ch], as_v = att_s[ch], ad_v = att_d[ch];
        #pragma unroll
        for (int r = 0; r < 4; ++r) {
            int row = rowbase + quad * 4 + r;
            float val = acc[nt][r] + cv;
            if (row < N) ((unsigned short*)h1bf)[(size_t)row * 128 + ch] = bfbits(val);
            if (nt < 4) { ps0[r] += val * as_v; pd0[r] += val * ad_v; }
            else        { ps1[r] += val * as_v; pd1[r] += val * ad_v; }
        }
    }
    #pragma unroll
    for (int r = 0; r < 4; ++r) {
        int row = rowbase + quad * 4 + r;
        float v0 = ps0[r], v1 = ps1[r], v2 = pd0[r], v3 = pd1[r];
        #pragma unroll
        for (int off = 1; off < 16; off <<= 1) {
            v0 += __shfl_xor(v0, off, 64); v1 += __shfl_xor(v1, off, 64);
            v2 += __shfl_xor(v2, off, 64); v3 += __shfl_xor(v3, off, 64);
        }
        if (lo == 0 && row < N) {
            a_src[row * 2 + 0] = v0; a_src[row * 2 + 1] = v1;
            a_dst[row * 2 + 0] = v2; a_dst[row * 2 + 1] = v3;
        }
    }
}

// ---- agg1: wave per dst; softmax + bf16 gather + bias + ELU -> hmid bf16 ----
__global__ void __launch_bounds__(256) agg1_csr_kernel(
        const int* __restrict__ row, const int* __restrict__ eid, const int* __restrict__ src,
        const float* __restrict__ a_src, const float* __restrict__ a_dst,
        const unsigned* __restrict__ h1u, const float* __restrict__ bias1,
        unsigned* __restrict__ hmid_u, int N) {
    int d = blockIdx.x * 4 + (threadIdx.x >> 6);
    if (d >= N) return;
    int lane = threadIdx.x & 63;
    int beg = row[d], end = row[d + 1];
    float ad0 = a_dst[d * 2 + 0], ad1 = a_dst[d * 2 + 1];
    float den0 = 0.f, den1 = 0.f;
    for (int b = beg; b < end; b += 64) {
        int i = b + lane;
        if (i < end) {
            int s = src[eid[i]];
            float v0 = a_src[s * 2 + 0] + ad0; v0 = v0 > 0.f ? v0 : 0.2f * v0;
            float v1 = a_src[s * 2 + 1] + ad1; v1 = v1 > 0.f ? v1 : 0.2f * v1;
            den0 += __expf(v0); den1 += __expf(v1);
        }
    }
    den0 = wave_allreduce_sum(den0);
    den1 = wave_allreduce_sum(den1);
    float inv0 = 1.f / (den0 + 1e-16f);
    float inv1 = 1.f / (den1 + 1e-16f);
    float accA = 0.f, accB = 0.f;  // channels 2*lane, 2*lane+1
    bool head0 = lane < 32;
    for (int b = beg; b < end; b += 64) {
        int cnt = min(64, end - b);
        int i = b + lane;
        int s = 0; float ex0 = 0.f, ex1 = 0.f;
        if (i < end) {
            s = src[eid[i]];
            float v0 = a_src[s * 2 + 0] + ad0; v0 = v0 > 0.f ? v0 : 0.2f * v0;
            float v1 = a_src[s * 2 + 1] + ad1; v1 = v1 > 0.f ? v1 : 0.2f * v1;
            ex0 = __expf(v0); ex1 = __expf(v1);
        }
        for (int j = 0; j < cnt; ++j) {
            float al0 = __shfl(ex0, j, 64) * inv0;
            float al1 = __shfl(ex1, j, 64) * inv1;
            int sj = __shfl(s, j, 64);
            unsigned u = h1u[(size_t)sj * 64 + lane];
            float w = head0 ? al0 : al1;
            accA += bf16lo(u) * w;
            accB += bf16hi(u) * w;
        }
    }
    int c = 2 * lane;
    float v0 = accA + bias1[c];
    float v1 = accB + bias1[c + 1];
    v0 = v0 > 0.f ? v0 : expm1f(v0);
    v1 = v1 > 0.f ? v1 : expm1f(v1);
    hmid_u[(size_t)d * 64 + lane] = ((unsigned)bfbits(v1) << 16) | (unsigned)bfbits(v0);
}

// ---- gemm2 MFMA: h2pre[N,256](bf16) = hmid @ W2frag ; logits a_s2/a_d2 ----
__global__ void __launch_bounds__(256) gemm2_mfma_kernel(
        const __hip_bfloat16* __restrict__ hmid, const __hip_bfloat16* __restrict__ wfrag,
        const float* __restrict__ att_s, const float* __restrict__ att_d,
        __hip_bfloat16* __restrict__ h2pre, float* __restrict__ a_src, float* __restrict__ a_dst, int N) {
    int lane = threadIdx.x & 63, wv = threadIdx.x >> 6;
    int lo = lane & 15, quad = lane >> 4;
    int rowbase = (blockIdx.x * 4 + wv) * 16;
    if (rowbase >= N) return;
    int arow = rowbase + lo; if (arow >= N) arow = N - 1;
    const __hip_bfloat16* ap = hmid + (size_t)arow * 128 + quad * 8;
    floatx4 acc[16];
    #pragma unroll
    for (int nt = 0; nt < 16; ++nt) acc[nt] = (floatx4){0.f, 0.f, 0.f, 0.f};
    const short8* bf = (const short8*)wfrag;
    #pragma unroll
    for (int kt = 0; kt < 4; ++kt) {
        short8 a = *(const short8*)(ap + kt * 32);
        #pragma unroll
        for (int nt = 0; nt < 16; ++nt)
            acc[nt] = __builtin_amdgcn_mfma_f32_16x16x32_bf16(a, bf[(kt * 16 + nt) * 64 + lane], acc[nt], 0, 0, 0);
    }
    float ps0[4] = {0,0,0,0}, ps1[4] = {0,0,0,0}, pd0[4] = {0,0,0,0}, pd1[4] = {0,0,0,0};
    #pragma unroll
    for (int nt = 0; nt < 16; ++nt) {
        int ch = nt * 16 + lo;
        float as_v = att_s[ch], ad_v = att_d[ch];
        #pragma unroll
        for (int r = 0; r < 4; ++r) {
            int row = rowbase + quad * 4 + r;
            float val = acc[nt][r];
            if (row < N) ((unsigned short*)h2pre)[(size_t)row * 256 + ch] = bfbits(val);
            if (nt < 8) { ps0[r] += val * as_v; pd0[r] += val * ad_v; }
            else        { ps1[r] += val * as_v; pd1[r] += val * ad_v; }
        }
    }
    #pragma unroll
    for (int r = 0; r < 4; ++r) {
        int row = rowbase + quad * 4 + r;
        float v0 = ps0[r], v1 = ps1[r], v2 = pd0[r], v3 = pd1[r];
        #pragma unroll
        for (int off = 1; off < 16; off <<= 1) {
            v0 += __shfl_xor(v0, off, 64); v1 += __shfl_xor(v1, off, 64);
            v2 += __shfl_xor(v2, off, 64); v3 += __shfl_xor(v3, off, 64);
        }
        if (lo == 0 && row < N) {
            a_src[row * 2 + 0] = v0; a_src[row * 2 + 1] = v1;
            a_dst[row * 2 + 0] = v2; a_dst[row * 2 + 1] = v3;
        }
    }
}

// ---- agg2: wave per dst; softmax + bf16 gather + head-mean + bias -> h2bf ----
__global__ void __launch_bounds__(256) agg2_csr_kernel(
        const int* __restrict__ row, const int* __restrict__ eid, const int* __restrict__ src,
        const float* __restrict__ a_src, const float* __restrict__ a_dst,
        const unsigned* __restrict__ h2u, const float* __restrict__ bias2,
        unsigned* __restrict__ h2bf_u, int N) {
    int d = blockIdx.x * 4 + (threadIdx.x >> 6);
    if (d >= N) return;
    int lane = threadIdx.x & 63;
    int beg = row[d], end = row[d + 1];
    float ad0 = a_dst[d * 2 + 0], ad1 = a_dst[d * 2 + 1];
    float den0 = 0.f, den1 = 0.f;
    for (int b = beg; b < end; b += 64) {
        int i = b + lane;
        if (i < end) {
            int s = src[eid[i]];
            float v0 = a_src[s * 2 + 0] + ad0; v0 = v0 > 0.f ? v0 : 0.2f * v0;
            float v1 = a_src[s * 2 + 1] + ad1; v1 = v1 > 0.f ? v1 : 0.2f * v1;
            den0 += __expf(v0); den1 += __expf(v1);
        }
    }
    den0 = wave_allreduce_sum(den0);
    den1 = wave_allreduce_sum(den1);
    float inv0 = 0.5f / (den0 + 1e-16f);
    float inv1 = 0.5f / (den1 + 1e-16f);
    float accA = 0.f, accB = 0.f;
    for (int b = beg; b < end; b += 64) {
        int cnt = min(64, end - b);
        int i = b + lane;
        int s = 0; float ex0 = 0.f, ex1 = 0.f;
        if (i < end) {
            s = src[eid[i]];
            float v0 = a_src[s * 2 + 0] + ad0; v0 = v0 > 0.f ? v0 : 0.2f * v0;
            float v1 = a_src[s * 2 + 1] + ad1; v1 = v1 > 0.f ? v1 : 0.2f * v1;
            ex0 = __expf(v0); ex1 = __expf(v1);
        }
        for (int j = 0; j < cnt; ++j) {
            float al0 = __shfl(ex0, j, 64) * inv0;
            float al1 = __shfl(ex1, j, 64) * inv1;
            int sj = __shfl(s, j, 64);
            unsigned u0 = h2u[(size_t)sj * 128 + lane];
            unsigned u1 = h2u[(size_t)sj * 128 + 64 + lane];
            accA += bf16lo(u0) * al0 + bf16lo(u1) * al1;
            accB += bf16hi(u0) * al0 + bf16hi(u1) * al1;
        }
    }
    int c = 2 * lane;
    float oa = accA + bias2[c];
    float ob = accB + bias2[c + 1];
    h2bf_u[(size_t)d * 64 + lane] = ((unsigned)bfbits(ob) << 16) | (unsigned)bfbits(oa);
}

// ---- zsd MFMA: zsd[N,256](bf16): [zs | zd + fc2_b] = h2bf @ fc2frag ----
__global__ void __launch_bounds__(256) zsd_mfma_kernel(
        const __hip_bfloat16* __restrict__ h2bf, const __hip_bfloat16* __restrict__ wfrag,
        const float* __restrict__ fc2_b, __hip_bfloat16* __restrict__ zsd, int N) {
    int lane = threadIdx.x & 63, wv = threadIdx.x >> 6;
    int lo = lane & 15, quad = lane >> 4;
    int rowbase = (blockIdx.x * 4 + wv) * 16;
    if (rowbase >= N) return;
    int arow = rowbase + lo; if (arow >= N) arow = N - 1;
    const __hip_bfloat16* ap = h2bf + (size_t)arow * 128 + quad * 8;
    floatx4 acc[16];
    #pragma unroll
    for (int nt = 0; nt < 16; ++nt) acc[nt] = (floatx4){0.f, 0.f, 0.f, 0.f};
    const short8* bf = (const short8*)wfrag;
    #pragma unroll
    for (int kt = 0; kt < 4; ++kt) {
        short8 a = *(const short8*)(ap + kt * 32);
        #pragma unroll
        for (int nt = 0; nt < 16; ++nt)
            acc[nt] = __builtin_amdgcn_mfma_f32_16x16x32_bf16(a, bf[(kt * 16 + nt) * 64 + lane], acc[nt], 0, 0, 0);
    }
    #pragma unroll
    for (int nt = 0; nt < 16; ++nt) {
        int ch = nt * 16 + lo;
        float bv = (nt >= 8) ? fc2_b[ch - 128] : 0.f;
        #pragma unroll
        for (int r = 0; r < 4; ++r) {
            int row = rowbase + quad * 4 + r;
            if (row < N) ((unsigned short*)zsd)[(size_t)row * 256 + ch] = bfbits(acc[nt][r] + bv);
        }
    }
}

// ---- edge head: out[e] = sigmoid(fc3 . relu(zs[src] + zdb[dst]) + b3) ----
__global__ void __launch_bounds__(256) edge_zsd_kernel(
        const int* __restrict__ src, const int* __restrict__ dst,
        const unsigned* __restrict__ zsd_u, const float* __restrict__ fc3_w,
        const float* __restrict__ fc3_b, float* __restrict__ out, int E) {
    int lane = threadIdx.x & 63, wv = threadIdx.x >> 6;
    int base = blockIdx.x * 16 + wv * 4;
    if (base >= E) return;
    float f3a = fc3_w[2 * lane], f3b = fc3_w[2 * lane + 1];
    float b3 = fc3_b[0];
    unsigned us[4], ud[4];
    #pragma unroll
    for (int u = 0; u < 4; ++u) {
        int e = base + u; if (e >= E) e = E - 1;
        int s = src[e], d = dst[e];
        us[u] = zsd_u[(size_t)s * 128 + lane];
        ud[u] = zsd_u[(size_t)d * 128 + 64 + lane];
    }
    #pragma unroll
    for (int u = 0; u < 4; ++u) {
        float za = fmaxf(bf16lo(us[u]) + bf16lo(ud[u]), 0.f);
        float zb = fmaxf(bf16hi(us[u]) + bf16hi(ud[u]), 0.f);
        float p = za * f3a + zb * f3b;
        #pragma unroll
        for (int off = 1; off < 64; off <<= 1) p += __shfl_xor(p, off, 64);
        int e = base + u;
        if (lane == 0 && e < E)
            out[e] = 1.f / (1.f + expf(-(p + b3)));
    }
}

extern "C" void kernel_launch(void* const* d_in, const int* in_sizes, int n_in,
                              void* d_out, int out_size, void* d_ws, size_t ws_size,
                              hipStream_t stream) {
    const float* x      = (const float*)d_in[0];
    const int*   ei     = (const int*)d_in[1];
    const float* cls    = (const float*)d_in[2];
    const float* fc0_w  = (const float*)d_in[3];
    const float* fc0_b  = (const float*)d_in[4];
    const float* W1     = (const float*)d_in[5];
    const float* att_s1 = (const float*)d_in[6];
    const float* att_d1 = (const float*)d_in[7];
    const float* bias1  = (const float*)d_in[8];
    const float* W2     = (const float*)d_in[9];
    const float* att_s2 = (const float*)d_in[10];
    const float* att_d2 = (const float*)d_in[11];
    const float* bias2  = (const float*)d_in[12];
    const float* fc2_w  = (const float*)d_in[13];
    const float* fc2_b  = (const float*)d_in[14];
    const float* fc3_w  = (const float*)d_in[15];
    const float* fc3_b  = (const float*)d_in[16];
    float* out = (float*)d_out;

    int N = in_sizes[0] / 128;
    int E = in_sizes[1] / 2;
    const int* src = ei;
    const int* dst = ei + E;

    float* w = (float*)d_ws;
    size_t off = 0;
    auto alloc = [&](size_t n) { float* p = w + off; off += (n + 63) & ~(size_t)63; return p; };
    float* c1      = alloc(128);
    float* w1fragf = alloc(16384 / 2);
    float* w2fragf = alloc(32768 / 2);
    float* fc2fragf= alloc(32768 / 2);
    float* a_s1    = alloc((size_t)N * 2);
    float* a_d1    = alloc((size_t)N * 2);
    float* a_s2    = alloc((size_t)N * 2);
    float* a_d2    = alloc((size_t)N * 2);
    float* xbff    = alloc((size_t)N * 64);   // N*128 bf16
    float* h1bff   = alloc((size_t)N * 64);   // N*128 bf16
    float* hmidf   = alloc((size_t)N * 64);   // N*128 bf16
    float* h2pref  = alloc((size_t)N * 128);  // N*256 bf16
    float* h2bff   = alloc((size_t)N * 64);   // N*128 bf16
    float* zsdf    = alloc((size_t)N * 128);  // N*256 bf16
    int* counts = (int*)alloc(N);
    int* rowp   = (int*)alloc(N + 1);
    int* woff   = (int*)alloc(N);
    int* eidb   = (int*)alloc(E);
    __hip_bfloat16* w1frag = (__hip_bfloat16*)w1fragf;
    __hip_bfloat16* w2frag = (__hip_bfloat16*)w2fragf;
    __hip_bfloat16* fc2frag= (__hip_bfloat16*)fc2fragf;
    __hip_bfloat16* xbf    = (__hip_bfloat16*)xbff;
    __hip_bfloat16* h1bf   = (__hip_bfloat16*)h1bff;
    __hip_bfloat16* hmid   = (__hip_bfloat16*)hmidf;
    __hip_bfloat16* h2pre  = (__hip_bfloat16*)h2pref;
    __hip_bfloat16* h2bf   = (__hip_bfloat16*)h2bff;
    __hip_bfloat16* zsd    = (__hip_bfloat16*)zsdf;

    hipMemsetAsync(counts, 0, sizeof(int) * (size_t)N, stream);

    prep_kernel<<<64, 256, 0, stream>>>(cls, fc0_w, fc0_b, W1, W2, fc2_w, c1, w1frag, w2frag, fc2frag);
    count_kernel<<<(E + 255) / 256, 256, 0, stream>>>(dst, counts, E);
    scan_kernel<<<1, 1024, 0, stream>>>(counts, rowp, woff, N, E);
    scatter_kernel<<<(E + 255) / 256, 256, 0, stream>>>(dst, woff, eidb, E);
    cvt_bf16_kernel<<<(N * 64 + 255) / 256, 256, 0, stream>>>(x, (unsigned*)xbf, N * 64);
    gemm1_mfma_kernel<<<(N + 63) / 64, 256, 0, stream>>>(xbf, w1frag, c1, att_s1, att_d1, h1bf, a_s1, a_d1, N);
    agg1_csr_kernel<<<(N + 3) / 4, 256, 0, stream>>>(rowp, eidb, src, a_s1, a_d1, (const unsigned*)h1bf, bias1, (unsigned*)hmid, N);
    gemm2_mfma_kernel<<<(N + 63) / 64, 256, 0, stream>>>(hmid, w2frag, att_s2, att_d2, h2pre, a_s2, a_d2, N);
    agg2_csr_kernel<<<(N + 3) / 4, 256, 0, stream>>>(rowp, eidb, src, a_s2, a_d2, (const unsigned*)h2pre, bias2, (unsigned*)h2bf, N);
    zsd_mfma_kernel<<<(N + 63) / 64, 256, 0, stream>>>(h2bf, fc2frag, fc2_b, zsd, N);
    edge_zsd_kernel<<<(E + 15) / 16, 256, 0, stream>>>(src, dst, (const unsigned*)zsd, fc3_w, fc3_b, out, E);
}

// Round 5
// 366.465 us; speedup vs baseline: 5.0429x; 1.2230x over previous
//
#include <hip/hip_runtime.h>
#include <hip/hip_bf16.h>
#include <math.h>

// N=50000, E=500000, SED=128, HID=64, H=2, F_node=128
// Round 5: vectorized CSR aggregation (16B/lane gathers, multi-edge rounds,
// register-cached softmax terms), srcs[] instead of eid[], 3-kernel scan,
// cvt fused into gemm1. MFMA node GEMMs + algebraic edge head unchanged.

typedef short short8 __attribute__((ext_vector_type(8)));
typedef float floatx4 __attribute__((ext_vector_type(4)));

__device__ __forceinline__ float wave_allreduce_sum(float v) {
    #pragma unroll
    for (int off = 1; off < 64; off <<= 1) v += __shfl_xor(v, off, 64);
    return v;
}
__device__ __forceinline__ float bf16lo(unsigned u) {
    unsigned x = u << 16; return __builtin_bit_cast(float, x);
}
__device__ __forceinline__ float bf16hi(unsigned u) {
    unsigned x = u & 0xFFFF0000u; return __builtin_bit_cast(float, x);
}
__device__ __forceinline__ unsigned short bfbits(float f) {
    return __builtin_bit_cast(unsigned short, __float2bfloat16(f));
}
__device__ __forceinline__ unsigned packbf(float a, float b) {
    return ((unsigned)bfbits(b) << 16) | (unsigned)bfbits(a);
}

// ---- prep: sent/c1; bf16 B-fragment tables for W1, W2, fc2(split) ----
__global__ void prep_kernel(const float* __restrict__ cls, const float* __restrict__ fc0_w,
                            const float* __restrict__ fc0_b, const float* __restrict__ W1,
                            const float* __restrict__ W2, const float* __restrict__ fc2_w,
                            float* __restrict__ c1,
                            __hip_bfloat16* __restrict__ w1frag,
                            __hip_bfloat16* __restrict__ w2frag,
                            __hip_bfloat16* __restrict__ fc2frag) {
    int tid = threadIdx.x;
    if (blockIdx.x == 0) {
        __shared__ float s_sent[128];
        if (tid < 128) {
            float acc = fc0_b[tid];
            const float* row = fc0_w + (size_t)tid * 768;
            for (int k = 0; k < 768; ++k) acc += row[k] * cls[k];
            s_sent[tid] = acc;
        }
        __syncthreads();
        if (tid < 128) {
            float acc = 0.f;
            for (int k = 0; k < 128; ++k) acc += s_sent[k] * W1[(128 + k) * 128 + tid];
            c1[tid] = acc;
        }
    }
    int gstride = gridDim.x * blockDim.x;
    int g = blockIdx.x * blockDim.x + tid;
    for (int i = g; i < 16384; i += gstride) {
        int j = i & 7, l = (i >> 3) & 63, nt = (i >> 9) & 7, kt = (i >> 12) & 3;
        int k = kt * 32 + (l >> 4) * 8 + j;
        int n = nt * 16 + (l & 15);
        w1frag[i] = __float2bfloat16(W1[k * 128 + n]);
    }
    for (int i = g; i < 32768; i += gstride) {
        int j = i & 7, l = (i >> 3) & 63, nt = (i >> 9) & 15, kt = (i >> 13) & 3;
        int k = kt * 32 + (l >> 4) * 8 + j;
        int n = nt * 16 + (l & 15);
        w2frag[i] = __float2bfloat16(W2[k * 256 + n]);
    }
    for (int i = g; i < 32768; i += gstride) {
        int j = i & 7, l = (i >> 3) & 63, nt = (i >> 9) & 15, kt = (i >> 13) & 3;
        int k = kt * 32 + (l >> 4) * 8 + j;
        int n = nt * 16 + (l & 15);
        float v = (n < 128) ? fc2_w[n * 256 + k] : fc2_w[(n - 128) * 256 + 128 + k];
        fc2frag[i] = __float2bfloat16(v);
    }
}

// ---- CSR build ----
__global__ void count_kernel(const int* __restrict__ dst, int* __restrict__ counts, int E) {
    int e = blockIdx.x * blockDim.x + threadIdx.x;
    if (e < E) atomicAdd(&counts[dst[e]], 1);
}

__global__ void __launch_bounds__(256) bsum_kernel(const int* __restrict__ counts,
                                                   int* __restrict__ bsum, int N) {
    int base = blockIdx.x * 1024;
    int tid = threadIdx.x;
    int v = 0;
    #pragma unroll
    for (int k = 0; k < 4; ++k) {
        int idx = base + k * 256 + tid;
        if (idx < N) v += counts[idx];
    }
    #pragma unroll
    for (int off = 1; off < 64; off <<= 1) v += __shfl_xor(v, off, 64);
    __shared__ int ws[4];
    if ((tid & 63) == 0) ws[tid >> 6] = v;
    __syncthreads();
    if (tid == 0) bsum[blockIdx.x] = ws[0] + ws[1] + ws[2] + ws[3];
}

__global__ void top_scan_kernel(const int* __restrict__ bsum, int* __restrict__ boff, int nb) {
    int lane = threadIdx.x;
    int v = (lane < nb) ? bsum[lane] : 0;
    int x = v;
    #pragma unroll
    for (int off = 1; off < 64; off <<= 1) {
        int t = __shfl_up(x, off, 64);
        if (lane >= off) x += t;
    }
    if (lane < nb) boff[lane] = x - v;
}

__global__ void __launch_bounds__(1024) local_scan_kernel(const int* __restrict__ counts,
                                                          const int* __restrict__ boff,
                                                          int* __restrict__ row, int* __restrict__ woff,
                                                          int N, int E) {
    int tid = threadIdx.x, lane = tid & 63, wv = tid >> 6;
    int base = blockIdx.x * 1024;
    __shared__ int wsum[16];
    int v = (base + tid < N) ? counts[base + tid] : 0;
    int x = v;
    #pragma unroll
    for (int off = 1; off < 64; off <<= 1) {
        int t = __shfl_up(x, off, 64);
        if (lane >= off) x += t;
    }
    if (lane == 63) wsum[wv] = x;
    __syncthreads();
    if (wv == 0 && lane < 16) {
        int y = wsum[lane];
        #pragma unroll
        for (int off = 1; off < 16; off <<= 1) {
            int t = __shfl_up(y, off, 64);
            if (lane >= off) y += t;
        }
        wsum[lane] = y;
    }
    __syncthreads();
    int excl = boff[blockIdx.x] + (wv ? wsum[wv - 1] : 0) + x - v;
    if (base + tid < N) { row[base + tid] = excl; woff[base + tid] = excl; }
    if (blockIdx.x == 0 && tid == 0) row[N] = E;
}

__global__ void scatter_kernel(const int* __restrict__ src, const int* __restrict__ dst,
                               int* __restrict__ woff, int* __restrict__ srcs, int E) {
    int e = blockIdx.x * blockDim.x + threadIdx.x;
    if (e < E) {
        int pos = atomicAdd(&woff[dst[e]], 1);
        srcs[pos] = src[e];
    }
}

// ---- gemm1 MFMA (cvt fused): h1bf = bf16(x) @ W1frag + c1 ; logits ----
__global__ void __launch_bounds__(256) gemm1_mfma_kernel(
        const float* __restrict__ x, const __hip_bfloat16* __restrict__ wfrag,
        const float* __restrict__ c1, const float* __restrict__ att_s, const float* __restrict__ att_d,
        __hip_bfloat16* __restrict__ h1bf, float* __restrict__ a_src, float* __restrict__ a_dst, int N) {
    int lane = threadIdx.x & 63, wv = threadIdx.x >> 6;
    int lo = lane & 15, quad = lane >> 4;
    int rowbase = (blockIdx.x * 4 + wv) * 16;
    if (rowbase >= N) return;
    int arow = rowbase + lo; if (arow >= N) arow = N - 1;
    const float* ap = x + (size_t)arow * 128 + quad * 8;
    floatx4 acc[8];
    #pragma unroll
    for (int nt = 0; nt < 8; ++nt) acc[nt] = (floatx4){0.f, 0.f, 0.f, 0.f};
    const short8* bf = (const short8*)wfrag;
    #pragma unroll
    for (int kt = 0; kt < 4; ++kt) {
        float4 fa = *(const float4*)(ap + kt * 32);
        float4 fb = *(const float4*)(ap + kt * 32 + 4);
        short8 a;
        a[0] = (short)bfbits(fa.x); a[1] = (short)bfbits(fa.y);
        a[2] = (short)bfbits(fa.z); a[3] = (short)bfbits(fa.w);
        a[4] = (short)bfbits(fb.x); a[5] = (short)bfbits(fb.y);
        a[6] = (short)bfbits(fb.z); a[7] = (short)bfbits(fb.w);
        #pragma unroll
        for (int nt = 0; nt < 8; ++nt)
            acc[nt] = __builtin_amdgcn_mfma_f32_16x16x32_bf16(a, bf[(kt * 8 + nt) * 64 + lane], acc[nt], 0, 0, 0);
    }
    float ps0[4] = {0,0,0,0}, ps1[4] = {0,0,0,0}, pd0[4] = {0,0,0,0}, pd1[4] = {0,0,0,0};
    #pragma unroll
    for (int nt = 0; nt < 8; ++nt) {
        int ch = nt * 16 + lo;
        float cv = c1[ch], as_v = att_s[ch], ad_v = att_d[ch];
        #pragma unroll
        for (int r = 0; r < 4; ++r) {
            int row = rowbase + quad * 4 + r;
            float val = acc[nt][r] + cv;
            if (row < N) ((unsigned short*)h1bf)[(size_t)row * 128 + ch] = bfbits(val);
            if (nt < 4) { ps0[r] += val * as_v; pd0[r] += val * ad_v; }
            else        { ps1[r] += val * as_v; pd1[r] += val * ad_v; }
        }
    }
    #pragma unroll
    for (int r = 0; r < 4; ++r) {
        int row = rowbase + quad * 4 + r;
        float v0 = ps0[r], v1 = ps1[r], v2 = pd0[r], v3 = pd1[r];
        #pragma unroll
        for (int off = 1; off < 16; off <<= 1) {
            v0 += __shfl_xor(v0, off, 64); v1 += __shfl_xor(v1, off, 64);
            v2 += __shfl_xor(v2, off, 64); v3 += __shfl_xor(v3, off, 64);
        }
        if (lo == 0 && row < N) {
            a_src[row * 2 + 0] = v0; a_src[row * 2 + 1] = v1;
            a_dst[row * 2 + 0] = v2; a_dst[row * 2 + 1] = v3;
        }
    }
}

// ---- agg1: wave/dst, 4 edges per round, 16B/lane gather; bias+ELU -> hmid bf16 ----
__global__ void __launch_bounds__(256) agg1_csr_kernel(
        const int* __restrict__ row, const int* __restrict__ srcs,
        const float* __restrict__ a_src, const float* __restrict__ a_dst,
        const unsigned* __restrict__ h1u, const float* __restrict__ bias1,
        unsigned* __restrict__ hmid_u, int N) {
    int d = blockIdx.x * 4 + (threadIdx.x >> 6);
    if (d >= N) return;
    int lane = threadIdx.x & 63;
    int beg = row[d], end = row[d + 1];
    float ad0 = a_dst[d * 2 + 0], ad1 = a_dst[d * 2 + 1];
    // denominators; cache first-batch terms in registers (avg degree 10 => one batch)
    int s_c = 0; float e0_c = 0.f, e1_c = 0.f;
    {
        int i = beg + lane;
        if (i < end) {
            s_c = srcs[i];
            float v0 = a_src[s_c * 2 + 0] + ad0; v0 = v0 > 0.f ? v0 : 0.2f * v0;
            float v1 = a_src[s_c * 2 + 1] + ad1; v1 = v1 > 0.f ? v1 : 0.2f * v1;
            e0_c = __expf(v0); e1_c = __expf(v1);
        }
    }
    float den0 = e0_c, den1 = e1_c;
    for (int b = beg + 64; b < end; b += 64) {
        int i = b + lane;
        if (i < end) {
            int s = srcs[i];
            float v0 = a_src[s * 2 + 0] + ad0; v0 = v0 > 0.f ? v0 : 0.2f * v0;
            float v1 = a_src[s * 2 + 1] + ad1; v1 = v1 > 0.f ? v1 : 0.2f * v1;
            den0 += __expf(v0); den1 += __expf(v1);
        }
    }
    den0 = wave_allreduce_sum(den0);
    den1 = wave_allreduce_sum(den1);
    float inv0 = 1.f / (den0 + 1e-16f);
    float inv1 = 1.f / (den1 + 1e-16f);

    int g = lane >> 4, q = lane & 15;
    float facc[8];
    #pragma unroll
    for (int m = 0; m < 8; ++m) facc[m] = 0.f;
    for (int b = beg; b < end; b += 64) {
        int i = b + lane;
        int s = 0; float e0 = 0.f, e1 = 0.f;
        if (b == beg) { s = s_c; e0 = e0_c; e1 = e1_c; }
        else if (i < end) {
            s = srcs[i];
            float v0 = a_src[s * 2 + 0] + ad0; v0 = v0 > 0.f ? v0 : 0.2f * v0;
            float v1 = a_src[s * 2 + 1] + ad1; v1 = v1 > 0.f ? v1 : 0.2f * v1;
            e0 = __expf(v0); e1 = __expf(v1);
        }
        int cnt = min(64, end - b);
        int rounds = (cnt + 3) >> 2;
        for (int j = 0; j < rounds; ++j) {
            int sl = 4 * j + g;
            float al0 = __shfl(e0, sl, 64) * inv0;
            float al1 = __shfl(e1, sl, 64) * inv1;
            int   sj  = __shfl(s,  sl, 64);
            float wgt = (q < 8) ? al0 : al1;
            uint4 u = ((const uint4*)(h1u + (size_t)sj * 64))[q];
            facc[0] += bf16lo(u.x) * wgt; facc[1] += bf16hi(u.x) * wgt;
            facc[2] += bf16lo(u.y) * wgt; facc[3] += bf16hi(u.y) * wgt;
            facc[4] += bf16lo(u.z) * wgt; facc[5] += bf16hi(u.z) * wgt;
            facc[6] += bf16lo(u.w) * wgt; facc[7] += bf16hi(u.w) * wgt;
        }
    }
    #pragma unroll
    for (int m = 0; m < 8; ++m) {
        facc[m] += __shfl_xor(facc[m], 16, 64);
        facc[m] += __shfl_xor(facc[m], 32, 64);
    }
    if (lane < 16) {
        int c0 = 8 * q;
        float v[8];
        #pragma unroll
        for (int m = 0; m < 8; ++m) {
            float vv = facc[m] + bias1[c0 + m];
            v[m] = vv > 0.f ? vv : expm1f(vv);
        }
        uint4 o;
        o.x = packbf(v[0], v[1]); o.y = packbf(v[2], v[3]);
        o.z = packbf(v[4], v[5]); o.w = packbf(v[6], v[7]);
        ((uint4*)(hmid_u + (size_t)d * 64))[q] = o;
    }
}

// ---- gemm2 MFMA: h2pre[N,256](bf16) = hmid @ W2frag ; logits ----
__global__ void __launch_bounds__(256) gemm2_mfma_kernel(
        const __hip_bfloat16* __restrict__ hmid, const __hip_bfloat16* __restrict__ wfrag,
        const float* __restrict__ att_s, const float* __restrict__ att_d,
        __hip_bfloat16* __restrict__ h2pre, float* __restrict__ a_src, float* __restrict__ a_dst, int N) {
    int lane = threadIdx.x & 63, wv = threadIdx.x >> 6;
    int lo = lane & 15, quad = lane >> 4;
    int rowbase = (blockIdx.x * 4 + wv) * 16;
    if (rowbase >= N) return;
    int arow = rowbase + lo; if (arow >= N) arow = N - 1;
    const __hip_bfloat16* ap = hmid + (size_t)arow * 128 + quad * 8;
    floatx4 acc[16];
    #pragma unroll
    for (int nt = 0; nt < 16; ++nt) acc[nt] = (floatx4){0.f, 0.f, 0.f, 0.f};
    const short8* bf = (const short8*)wfrag;
    #pragma unroll
    for (int kt = 0; kt < 4; ++kt) {
        short8 a = *(const short8*)(ap + kt * 32);
        #pragma unroll
        for (int nt = 0; nt < 16; ++nt)
            acc[nt] = __builtin_amdgcn_mfma_f32_16x16x32_bf16(a, bf[(kt * 16 + nt) * 64 + lane], acc[nt], 0, 0, 0);
    }
    float ps0[4] = {0,0,0,0}, ps1[4] = {0,0,0,0}, pd0[4] = {0,0,0,0}, pd1[4] = {0,0,0,0};
    #pragma unroll
    for (int nt = 0; nt < 16; ++nt) {
        int ch = nt * 16 + lo;
        float as_v = att_s[ch], ad_v = att_d[ch];
        #pragma unroll
        for (int r = 0; r < 4; ++r) {
            int row = rowbase + quad * 4 + r;
            float val = acc[nt][r];
            if (row < N) ((unsigned short*)h2pre)[(size_t)row * 256 + ch] = bfbits(val);
            if (nt < 8) { ps0[r] += val * as_v; pd0[r] += val * ad_v; }
            else        { ps1[r] += val * as_v; pd1[r] += val * ad_v; }
        }
    }
    #pragma unroll
    for (int r = 0; r < 4; ++r) {
        int row = rowbase + quad * 4 + r;
        float v0 = ps0[r], v1 = ps1[r], v2 = pd0[r], v3 = pd1[r];
        #pragma unroll
        for (int off = 1; off < 16; off <<= 1) {
            v0 += __shfl_xor(v0, off, 64); v1 += __shfl_xor(v1, off, 64);
            v2 += __shfl_xor(v2, off, 64); v3 += __shfl_xor(v3, off, 64);
        }
        if (lo == 0 && row < N) {
            a_src[row * 2 + 0] = v0; a_src[row * 2 + 1] = v1;
            a_dst[row * 2 + 0] = v2; a_dst[row * 2 + 1] = v3;
        }
    }
}

// ---- agg2: wave/dst, 2 edges per round, 16B/lane gather; head-mean+bias -> h2bf ----
__global__ void __launch_bounds__(256) agg2_csr_kernel(
        const int* __restrict__ row, const int* __restrict__ srcs,
        const float* __restrict__ a_src, const float* __restrict__ a_dst,
        const unsigned* __restrict__ h2u, const float* __restrict__ bias2,
        unsigned* __restrict__ h2bf_u, int N) {
    int d = blockIdx.x * 4 + (threadIdx.x >> 6);
    if (d >= N) return;
    int lane = threadIdx.x & 63;
    int beg = row[d], end = row[d + 1];
    float ad0 = a_dst[d * 2 + 0], ad1 = a_dst[d * 2 + 1];
    int s_c = 0; float e0_c = 0.f, e1_c = 0.f;
    {
        int i = beg + lane;
        if (i < end) {
            s_c = srcs[i];
            float v0 = a_src[s_c * 2 + 0] + ad0; v0 = v0 > 0.f ? v0 : 0.2f * v0;
            float v1 = a_src[s_c * 2 + 1] + ad1; v1 = v1 > 0.f ? v1 : 0.2f * v1;
            e0_c = __expf(v0); e1_c = __expf(v1);
        }
    }
    float den0 = e0_c, den1 = e1_c;
    for (int b = beg + 64; b < end; b += 64) {
        int i = b + lane;
        if (i < end) {
            int s = srcs[i];
            float v0 = a_src[s * 2 + 0] + ad0; v0 = v0 > 0.f ? v0 : 0.2f * v0;
            float v1 = a_src[s * 2 + 1] + ad1; v1 = v1 > 0.f ? v1 : 0.2f * v1;
            den0 += __expf(v0); den1 += __expf(v1);
        }
    }
    den0 = wave_allreduce_sum(den0);
    den1 = wave_allreduce_sum(den1);
    float inv0 = 0.5f / (den0 + 1e-16f);   // fold head-mean
    float inv1 = 0.5f / (den1 + 1e-16f);

    int g = lane >> 5, q = lane & 31;
    float facc[8];
    #pragma unroll
    for (int m = 0; m < 8; ++m) facc[m] = 0.f;
    for (int b = beg; b < end; b += 64) {
        int i = b + lane;
        int s = 0; float e0 = 0.f, e1 = 0.f;
        if (b == beg) { s = s_c; e0 = e0_c; e1 = e1_c; }
        else if (i < end) {
            s = srcs[i];
            float v0 = a_src[s * 2 + 0] + ad0; v0 = v0 > 0.f ? v0 : 0.2f * v0;
            float v1 = a_src[s * 2 + 1] + ad1; v1 = v1 > 0.f ? v1 : 0.2f * v1;
            e0 = __expf(v0); e1 = __expf(v1);
        }
        int cnt = min(64, end - b);
        int rounds = (cnt + 1) >> 1;
        for (int j = 0; j < rounds; ++j) {
            int sl = 2 * j + g;
            float al0 = __shfl(e0, sl, 64) * inv0;
            float al1 = __shfl(e1, sl, 64) * inv1;
            int   sj  = __shfl(s,  sl, 64);
            float wgt = (q < 16) ? al0 : al1;
            uint4 u = ((const uint4*)(h2u + (size_t)sj * 128))[q];
            facc[0] += bf16lo(u.x) * wgt; facc[1] += bf16hi(u.x) * wgt;
            facc[2] += bf16lo(u.y) * wgt; facc[3] += bf16hi(u.y) * wgt;
            facc[4] += bf16lo(u.z) * wgt; facc[5] += bf16hi(u.z) * wgt;
            facc[6] += bf16lo(u.w) * wgt; facc[7] += bf16hi(u.w) * wgt;
        }
    }
    #pragma unroll
    for (int m = 0; m < 8; ++m) {
        facc[m] += __shfl_xor(facc[m], 32, 64);  // combine edge-parity groups
        facc[m] += __shfl_xor(facc[m], 16, 64);  // combine heads
    }
    if (lane < 16) {
        int c0 = 8 * lane;
        uint4 o;
        o.x = packbf(facc[0] + bias2[c0 + 0], facc[1] + bias2[c0 + 1]);
        o.y = packbf(facc[2] + bias2[c0 + 2], facc[3] + bias2[c0 + 3]);
        o.z = packbf(facc[4] + bias2[c0 + 4], facc[5] + bias2[c0 + 5]);
        o.w = packbf(facc[6] + bias2[c0 + 6], facc[7] + bias2[c0 + 7]);
        ((uint4*)(h2bf_u + (size_t)d * 64))[lane] = o;
    }
}

// ---- zsd MFMA: zsd[N,256](bf16): [zs | zd + fc2_b] = h2bf @ fc2frag ----
__global__ void __launch_bounds__(256) zsd_mfma_kernel(
        const __hip_bfloat16* __restrict__ h2bf, const __hip_bfloat16* __restrict__ wfrag,
        const float* __restrict__ fc2_b, __hip_bfloat16* __restrict__ zsd, int N) {
    int lane = threadIdx.x & 63, wv = threadIdx.x >> 6;
    int lo = lane & 15, quad = lane >> 4;
    int rowbase = (blockIdx.x * 4 + wv) * 16;
    if (rowbase >= N) return;
    int arow = rowbase + lo; if (arow >= N) arow = N - 1;
    const __hip_bfloat16* ap = h2bf + (size_t)arow * 128 + quad * 8;
    floatx4 acc[16];
    #pragma unroll
    for (int nt = 0; nt < 16; ++nt) acc[nt] = (floatx4){0.f, 0.f, 0.f, 0.f};
    const short8* bf = (const short8*)wfrag;
    #pragma unroll
    for (int kt = 0; kt < 4; ++kt) {
        short8 a = *(const short8*)(ap + kt * 32);
        #pragma unroll
        for (int nt = 0; nt < 16; ++nt)
            acc[nt] = __builtin_amdgcn_mfma_f32_16x16x32_bf16(a, bf[(kt * 16 + nt) * 64 + lane], acc[nt], 0, 0, 0);
    }
    #pragma unroll
    for (int nt = 0; nt < 16; ++nt) {
        int ch = nt * 16 + lo;
        float bv = (nt >= 8) ? fc2_b[ch - 128] : 0.f;
        #pragma unroll
        for (int r = 0; r < 4; ++r) {
            int row = rowbase + quad * 4 + r;
            if (row < N) ((unsigned short*)zsd)[(size_t)row * 256 + ch] = bfbits(acc[nt][r] + bv);
        }
    }
}

// ---- edge head: 2 edges/round, 4 rounds/wave; relu-add via shfl_xor(16) ----
__global__ void __launch_bounds__(256) edge_zsd_kernel(
        const int* __restrict__ src, const int* __restrict__ dst,
        const unsigned* __restrict__ zsd_u, const float* __restrict__ fc3_w,
        const float* __restrict__ fc3_b, float* __restrict__ out, int E) {
    int lane = threadIdx.x & 63, wv = threadIdx.x >> 6;
    int g = lane >> 5, r = (lane >> 4) & 1, q = lane & 15;
    int base = (blockIdx.x * 4 + wv) * 8;
    if (base >= E) return;
    float f3[8];
    #pragma unroll
    for (int m = 0; m < 8; ++m) f3[m] = fc3_w[8 * q + m];
    float b3 = fc3_b[0];
    #pragma unroll
    for (int j = 0; j < 4; ++j) {
        int e = base + 2 * j + g;
        int ec = e < E ? e : E - 1;
        int node = r ? dst[ec] : src[ec];
        uint4 mine = ((const uint4*)(zsd_u + (size_t)node * 128 + (r << 6)))[q];
        uint4 oth;
        oth.x = (unsigned)__shfl_xor((int)mine.x, 16, 64);
        oth.y = (unsigned)__shfl_xor((int)mine.y, 16, 64);
        oth.z = (unsigned)__shfl_xor((int)mine.z, 16, 64);
        oth.w = (unsigned)__shfl_xor((int)mine.w, 16, 64);
        float p = 0.f;
        p += fmaxf(bf16lo(mine.x) + bf16lo(oth.x), 0.f) * f3[0];
        p += fmaxf(bf16hi(mine.x) + bf16hi(oth.x), 0.f) * f3[1];
        p += fmaxf(bf16lo(mine.y) + bf16lo(oth.y), 0.f) * f3[2];
        p += fmaxf(bf16hi(mine.y) + bf16hi(oth.y), 0.f) * f3[3];
        p += fmaxf(bf16lo(mine.z) + bf16lo(oth.z), 0.f) * f3[4];
        p += fmaxf(bf16hi(mine.z) + bf16hi(oth.z), 0.f) * f3[5];
        p += fmaxf(bf16lo(mine.w) + bf16lo(oth.w), 0.f) * f3[6];
        p += fmaxf(bf16hi(mine.w) + bf16hi(oth.w), 0.f) * f3[7];
        #pragma unroll
        for (int off = 1; off < 32; off <<= 1) p += __shfl_xor(p, off, 64);
        if ((lane & 31) == 0 && e < E)
            out[e] = 1.f / (1.f + expf(-(0.5f * p + b3)));
    }
}

extern "C" void kernel_launch(void* const* d_in, const int* in_sizes, int n_in,
                              void* d_out, int out_size, void* d_ws, size_t ws_size,
                              hipStream_t stream) {
    const float* x      = (const float*)d_in[0];
    const int*   ei     = (const int*)d_in[1];
    const float* cls    = (const float*)d_in[2];
    const float* fc0_w  = (const float*)d_in[3];
    const float* fc0_b  = (const float*)d_in[4];
    const float* W1     = (const float*)d_in[5];
    const float* att_s1 = (const float*)d_in[6];
    const float* att_d1 = (const float*)d_in[7];
    const float* bias1  = (const float*)d_in[8];
    const float* W2     = (const float*)d_in[9];
    const float* att_s2 = (const float*)d_in[10];
    const float* att_d2 = (const float*)d_in[11];
    const float* bias2  = (const float*)d_in[12];
    const float* fc2_w  = (const float*)d_in[13];
    const float* fc2_b  = (const float*)d_in[14];
    const float* fc3_w  = (const float*)d_in[15];
    const float* fc3_b  = (const float*)d_in[16];
    float* out = (float*)d_out;

    int N = in_sizes[0] / 128;
    int E = in_sizes[1] / 2;
    const int* src = ei;
    const int* dst = ei + E;
    int nb = (N + 1023) / 1024;

    float* w = (float*)d_ws;
    size_t off = 0;
    auto alloc = [&](size_t n) { float* p = w + off; off += (n + 63) & ~(size_t)63; return p; };
    float* c1      = alloc(128);
    float* w1fragf = alloc(16384 / 2);
    float* w2fragf = alloc(32768 / 2);
    float* fc2fragf= alloc(32768 / 2);
    float* a_s1    = alloc((size_t)N * 2);
    float* a_d1    = alloc((size_t)N * 2);
    float* a_s2    = alloc((size_t)N * 2);
    float* a_d2    = alloc((size_t)N * 2);
    float* h1bff   = alloc((size_t)N * 64);   // N*128 bf16
    float* hmidf   = alloc((size_t)N * 64);   // N*128 bf16
    float* h2pref  = alloc((size_t)N * 128);  // N*256 bf16
    float* h2bff   = alloc((size_t)N * 64);   // N*128 bf16
    float* zsdf    = alloc((size_t)N * 128);  // N*256 bf16
    int* counts = (int*)alloc(N);
    int* rowp   = (int*)alloc(N + 1);
    int* woff   = (int*)alloc(N);
    int* srcs   = (int*)alloc(E);
    int* bsum   = (int*)alloc(64);
    int* boff   = (int*)alloc(64);
    __hip_bfloat16* w1frag = (__hip_bfloat16*)w1fragf;
    __hip_bfloat16* w2frag = (__hip_bfloat16*)w2fragf;
    __hip_bfloat16* fc2frag= (__hip_bfloat16*)fc2fragf;
    __hip_bfloat16* h1bf   = (__hip_bfloat16*)h1bff;
    __hip_bfloat16* hmid   = (__hip_bfloat16*)hmidf;
    __hip_bfloat16* h2pre  = (__hip_bfloat16*)h2pref;
    __hip_bfloat16* h2bf   = (__hip_bfloat16*)h2bff;
    __hip_bfloat16* zsd    = (__hip_bfloat16*)zsdf;

    hipMemsetAsync(counts, 0, sizeof(int) * (size_t)N, stream);

    prep_kernel<<<64, 256, 0, stream>>>(cls, fc0_w, fc0_b, W1, W2, fc2_w, c1, w1frag, w2frag, fc2frag);
    count_kernel<<<(E + 255) / 256, 256, 0, stream>>>(dst, counts, E);
    bsum_kernel<<<nb, 256, 0, stream>>>(counts, bsum, N);
    top_scan_kernel<<<1, 64, 0, stream>>>(bsum, boff, nb);
    local_scan_kernel<<<nb, 1024, 0, stream>>>(counts, boff, rowp, woff, N, E);
    scatter_kernel<<<(E + 255) / 256, 256, 0, stream>>>(src, dst, woff, srcs, E);
    gemm1_mfma_kernel<<<(N + 63) / 64, 256, 0, stream>>>(x, w1frag, c1, att_s1, att_d1, h1bf, a_s1, a_d1, N);
    agg1_csr_kernel<<<(N + 3) / 4, 256, 0, stream>>>(rowp, srcs, a_s1, a_d1, (const unsigned*)h1bf, bias1, (unsigned*)hmid, N);
    gemm2_mfma_kernel<<<(N + 63) / 64, 256, 0, stream>>>(hmid, w2frag, att_s2, att_d2, h2pre, a_s2, a_d2, N);
    agg2_csr_kernel<<<(N + 3) / 4, 256, 0, stream>>>(rowp, srcs, a_s2, a_d2, (const unsigned*)h2pre, bias2, (unsigned*)h2bf, N);
    zsd_mfma_kernel<<<(N + 63) / 64, 256, 0, stream>>>(h2bf, fc2frag, fc2_b, zsd, N);
    edge_zsd_kernel<<<(E + 31) / 32, 256, 0, stream>>>(src, dst, (const unsigned*)zsd, fc3_w, fc3_b, out, E);
}